// Round 1
// 442.944 us; speedup vs baseline: 1.2082x; 1.2082x over previous
//
#include <hip/hip_runtime.h>

// Problem constants (match reference)
constexpr int N_NODES = 100000;
constexpr int N_EDGES = 500000;
constexpr int HID     = 128;   // conv1/conv2 output dim
constexpr int OUT_D   = 64;    // conv3 output dim
constexpr int TOTN    = 2 * N_NODES;   // both networks concatenated

constexpr int ROW_BLKS = (N_NODES + 63) / 64;   // 1563 blocks of 64 rows
constexpr int N_PAD    = ROW_BLKS * 64;          // 100032 padded rows

constexpr int SCAN_BLK   = 256;
constexpr int SCAN_ELEMS = 1024;                                 // 4 per thread
constexpr int NBLK_SCAN  = (TOTN + SCAN_ELEMS - 1) / SCAN_ELEMS; // 196 (<=256)
static_assert(NBLK_SCAN <= SCAN_BLK, "scan partials must fit one block");

typedef __attribute__((ext_vector_type(8))) short short8;
typedef __attribute__((ext_vector_type(4))) float float4v;

// float -> bf16 (round-to-nearest-even), as raw ushort
__device__ __forceinline__ unsigned short f2bf(float f) {
    unsigned u = __float_as_uint(f);
    u += 0x7fffu + ((u >> 16) & 1u);
    return (unsigned short)(u >> 16);
}
// packed pair of bf16 (lo = even col, hi = odd col) -> two floats
__device__ __forceinline__ float2 bfp2f(unsigned u) {
    float2 r;
    r.x = __uint_as_float(u << 16);
    r.y = __uint_as_float(u & 0xffff0000u);
    return r;
}

// 8 bf16 (one uint4) scaled-accumulate into acc[0..7] (static indices only)
__device__ __forceinline__ void acc8(float* acc, uint4 u, float nm) {
    const float2 p0 = bfp2f(u.x), p1 = bfp2f(u.y), p2 = bfp2f(u.z), p3 = bfp2f(u.w);
    acc[0] = fmaf(p0.x, nm, acc[0]); acc[1] = fmaf(p0.y, nm, acc[1]);
    acc[2] = fmaf(p1.x, nm, acc[2]); acc[3] = fmaf(p1.y, nm, acc[3]);
    acc[4] = fmaf(p2.x, nm, acc[4]); acc[5] = fmaf(p2.y, nm, acc[5]);
    acc[6] = fmaf(p3.x, nm, acc[6]); acc[7] = fmaf(p3.y, nm, acc[7]);
}

// ---------- degree count, both networks in one pass (concat node space) ----------
__global__ void deg_count2(const int* __restrict__ s_ei, const int* __restrict__ t_ei,
                           int* __restrict__ deg) {
    const int i = blockIdx.x * blockDim.x + threadIdx.x;
    if (i < N_EDGES) {
        atomicAdd(&deg[s_ei[N_EDGES + i]], 1);
    } else if (i < 2 * N_EDGES) {
        atomicAdd(&deg[N_NODES + t_ei[N_EDGES + (i - N_EDGES)]], 1);
    }
}

// ---------- scan phase A: per-block sums of 1024 degrees ----------
__global__ void scan_block_sums(const int* __restrict__ deg, int* __restrict__ partial, int n) {
    __shared__ int sd[SCAN_BLK];
    const int base = blockIdx.x * SCAN_ELEMS;
    int sum = 0;
#pragma unroll
    for (int k = 0; k < 4; ++k) {
        const int idx = base + k * SCAN_BLK + threadIdx.x;
        if (idx < n) sum += deg[idx];
    }
    sd[threadIdx.x] = sum;
    __syncthreads();
    for (int o = SCAN_BLK / 2; o > 0; o >>= 1) {
        if (threadIdx.x < o) sd[threadIdx.x] += sd[threadIdx.x + o];
        __syncthreads();
    }
    if (threadIdx.x == 0) partial[blockIdx.x] = sd[0];
}

// ---------- scan phase B: exclusive-scan the (<=256) partials in place ----------
__global__ void scan_partials(int* __restrict__ partial, int np) {
    __shared__ int s[SCAN_BLK];
    const int t = threadIdx.x;
    const int v = (t < np) ? partial[t] : 0;
    s[t] = v;
    __syncthreads();
    for (int o = 1; o < SCAN_BLK; o <<= 1) {
        const int x = (t >= o) ? s[t - o] : 0;
        __syncthreads();
        if (t >= o) s[t] += x;
        __syncthreads();
    }
    if (t < np) partial[t] = s[t] - v;   // exclusive
}

// ---------- scan phase C: final offsets + cursor copy + dis = rsqrt(deg+1) ----------
__global__ void scan_final(const int* __restrict__ deg, const int* __restrict__ partial,
                           int* __restrict__ off, int* __restrict__ cur,
                           float* __restrict__ dis, int n) {
    __shared__ int s[SCAN_BLK];
    const int t = threadIdx.x;
    const int base = blockIdx.x * SCAN_ELEMS + t * 4;
    int d0 = 0, d1 = 0, d2 = 0, d3 = 0;
    if (base + 0 < n) d0 = deg[base + 0];
    if (base + 1 < n) d1 = deg[base + 1];
    if (base + 2 < n) d2 = deg[base + 2];
    if (base + 3 < n) d3 = deg[base + 3];
    const int ts = d0 + d1 + d2 + d3;
    s[t] = ts;
    __syncthreads();
    for (int o = 1; o < SCAN_BLK; o <<= 1) {
        const int x = (t >= o) ? s[t - o] : 0;
        __syncthreads();
        if (t >= o) s[t] += x;
        __syncthreads();
    }
    int ex = s[t] - ts + partial[blockIdx.x];
    const int o0 = ex, o1 = ex + d0, o2 = o1 + d1, o3 = o2 + d2;
    if (base + 0 < n) { off[base + 0] = o0; cur[base + 0] = o0; dis[base + 0] = rsqrtf((float)d0 + 1.0f); }
    if (base + 1 < n) { off[base + 1] = o1; cur[base + 1] = o1; dis[base + 1] = rsqrtf((float)d1 + 1.0f); }
    if (base + 2 < n) { off[base + 2] = o2; cur[base + 2] = o2; dis[base + 2] = rsqrtf((float)d2 + 1.0f); }
    if (base + 3 < n) { off[base + 3] = o3; cur[base + 3] = o3; dis[base + 3] = rsqrtf((float)d3 + 1.0f); }
}

// ---------- bucket edges by dst (CSR build), both networks ----------
__global__ void bucket2(const int* __restrict__ s_ei, const int* __restrict__ t_ei,
                        int* __restrict__ cur, int* __restrict__ ebuf) {
    const int i = blockIdx.x * blockDim.x + threadIdx.x;
    if (i < N_EDGES) {
        const int d = s_ei[N_EDGES + i];
        const int pos = atomicAdd(&cur[d], 1);
        ebuf[pos] = s_ei[i];
    } else if (i < 2 * N_EDGES) {
        const int j = i - N_EDGES;
        const int d = t_ei[N_EDGES + j];
        const int pos = atomicAdd(&cur[N_NODES + d], 1);
        ebuf[pos] = t_ei[j];
    }
}

// ---------- pack all weights into MFMA B-fragment order, bf16, one launch ----------
__device__ __forceinline__ void pack_one(const float* __restrict__ W,
                                         unsigned short* __restrict__ Wp,
                                         int t, int COLS, int lg) {
    const int k = t >> lg, nn = t & (COLS - 1);
    const int kb = k >> 5, rem = k & 31, quad = rem >> 3, j = rem & 7;
    Wp[((size_t)(kb * 4 + quad) * COLS + nn) * 8 + j] = f2bf(W[t]);
}

__global__ void pack_all(const float* __restrict__ W1, const float* __restrict__ W2,
                         const float* __restrict__ W3,
                         unsigned short* __restrict__ Wp1, unsigned short* __restrict__ Wp2,
                         unsigned short* __restrict__ W3p) {
    const int idx = blockIdx.x * blockDim.x + threadIdx.x;
    if (idx < 128 * HID) {
        pack_one(W1, Wp1, idx, HID, 7);
    } else if (idx < 2 * 128 * HID) {
        pack_one(W2, Wp2, idx - 128 * HID, HID, 7);
    } else if (idx < 2 * 128 * HID + 128 * OUT_D) {
        pack_one(W3, W3p, idx - 2 * 128 * HID, OUT_D, 6);
    }
}

// ---------- MFMA GEMM with fused fp32->bf16 convert of A (both nets) ----------
template <int COLS>
__global__ __launch_bounds__(256) void mfma_gemm_f32(const float* __restrict__ X0,
                                                     const float* __restrict__ X1,
                                                     const unsigned short* __restrict__ Wp0,
                                                     const unsigned short* __restrict__ Wp1,
                                                     unsigned short* __restrict__ Y0,
                                                     unsigned short* __restrict__ Y1, int n) {
    const float* __restrict__ X = blockIdx.y ? X1 : X0;
    const unsigned short* __restrict__ Wp = blockIdx.y ? Wp1 : Wp0;
    unsigned short* __restrict__ Y = blockIdx.y ? Y1 : Y0;

    const int wave = threadIdx.x >> 6;
    const int lane = threadIdx.x & 63;
    const int quad = lane >> 4;
    const int l16  = lane & 15;
    const int rowbase = blockIdx.x * 64 + wave * 16;
    const int row = rowbase + l16;
    const int rc  = row < n ? row : n - 1;    // clamp: garbage rows never stored

    short8 a[4];
    const size_t arow = (size_t)rc * 128;
#pragma unroll
    for (int kb = 0; kb < 4; ++kb) {
        const float4 f0 = *(const float4*)&X[arow + kb * 32 + quad * 8];
        const float4 f1 = *(const float4*)&X[arow + kb * 32 + quad * 8 + 4];
        short8 v;
        v[0] = (short)f2bf(f0.x); v[1] = (short)f2bf(f0.y);
        v[2] = (short)f2bf(f0.z); v[3] = (short)f2bf(f0.w);
        v[4] = (short)f2bf(f1.x); v[5] = (short)f2bf(f1.y);
        v[6] = (short)f2bf(f1.z); v[7] = (short)f2bf(f1.w);
        a[kb] = v;
    }

#pragma unroll
    for (int ct = 0; ct < COLS / 16; ++ct) {
        const int col = ct * 16 + l16;
        float4v acc = {0.0f, 0.0f, 0.0f, 0.0f};
#pragma unroll
        for (int kb = 0; kb < 4; ++kb) {
            const short8 b = *(const short8*)&Wp[((size_t)(kb * 4 + quad) * COLS + col) * 8];
            acc = __builtin_amdgcn_mfma_f32_16x16x32_bf16(a[kb], b, acc, 0, 0, 0);
        }
#pragma unroll
        for (int r = 0; r < 4; ++r) {
            const int orow = rowbase + quad * 4 + r;   // C/D: row=(lane>>4)*4+reg, col=lane&15
            if (orow < n) Y[(size_t)orow * COLS + col] = f2bf(acc[r]);
        }
    }
}

// ---------- MFMA GEMM, bf16 input (conv3), both nets ----------
template <int COLS>
__global__ __launch_bounds__(256) void mfma_gemm_bf(const unsigned short* __restrict__ Xb0,
                                                    const unsigned short* __restrict__ Xb1,
                                                    const unsigned short* __restrict__ Wp,
                                                    unsigned short* __restrict__ Y0,
                                                    unsigned short* __restrict__ Y1, int n) {
    const unsigned short* __restrict__ Xb = blockIdx.y ? Xb1 : Xb0;
    unsigned short* __restrict__ Y = blockIdx.y ? Y1 : Y0;

    const int wave = threadIdx.x >> 6;
    const int lane = threadIdx.x & 63;
    const int quad = lane >> 4;
    const int l16  = lane & 15;
    const int rowbase = blockIdx.x * 64 + wave * 16;

    short8 a[4];
    const size_t arow = (size_t)(rowbase + l16) * 128;
#pragma unroll
    for (int kb = 0; kb < 4; ++kb)
        a[kb] = *(const short8*)&Xb[arow + kb * 32 + quad * 8];

#pragma unroll
    for (int ct = 0; ct < COLS / 16; ++ct) {
        const int col = ct * 16 + l16;
        float4v acc = {0.0f, 0.0f, 0.0f, 0.0f};
#pragma unroll
        for (int kb = 0; kb < 4; ++kb) {
            const short8 b = *(const short8*)&Wp[((size_t)(kb * 4 + quad) * COLS + col) * 8];
            acc = __builtin_amdgcn_mfma_f32_16x16x32_bf16(a[kb], b, acc, 0, 0, 0);
        }
#pragma unroll
        for (int r = 0; r < 4; ++r) {
            const int row = rowbase + quad * 4 + r;
            if (row < n) Y[(size_t)row * COLS + col] = f2bf(acc[r]);
        }
    }
}

// ---------- gather conv (128-d): 16 lanes/node, uint4 rows, 4 nodes/wave ----------
__global__ __launch_bounds__(256) void gather_relu_128_v2(
        const unsigned short* __restrict__ lin0, const unsigned short* __restrict__ lin1,
        const int* __restrict__ off, const int* __restrict__ degc,
        const int* __restrict__ ebuf, const float* __restrict__ dis,
        const float* __restrict__ bias0, const float* __restrict__ bias1,
        unsigned short* __restrict__ out0, unsigned short* __restrict__ out1, int n) {
    const int net = blockIdx.y;
    const unsigned short* __restrict__ lin = net ? lin1 : lin0;
    unsigned short* __restrict__ outb = net ? out1 : out0;
    const float* __restrict__ bias = net ? bias1 : bias0;

    const int wave = threadIdx.x >> 6;
    const int lane = threadIdx.x & 63;
    const int grp  = lane >> 4;          // 4 node-groups per wave
    const int l16  = lane & 15;          // 16 lanes x uint4(16B) = 256B row
    const int node = blockIdx.x * 16 + wave * 4 + grp;
    if (node >= n) return;

    const float* __restrict__ disb = dis + net * n;
    const int*   __restrict__ offb = off + net * n;
    const int*   __restrict__ degb = degc + net * n;

    const float ds  = disb[node];
    const float inv = ds * ds;                 // 1/(deg+1)
    const uint4* __restrict__ linv = (const uint4*)lin;   // row stride: 16 uint4

    float acc[8];
    {
        const uint4 su = linv[(size_t)node * 16 + l16];
        const float2 p0 = bfp2f(su.x), p1 = bfp2f(su.y), p2 = bfp2f(su.z), p3 = bfp2f(su.w);
        acc[0] = p0.x * inv; acc[1] = p0.y * inv;
        acc[2] = p1.x * inv; acc[3] = p1.y * inv;
        acc[4] = p2.x * inv; acc[5] = p2.y * inv;
        acc[6] = p3.x * inv; acc[7] = p3.y * inv;
    }

    const int start = offb[node];
    const int cnt   = degb[node];
    for (int j = 0; j < cnt; j += 4) {         // masked batches: no serial tail
        const int b0 = start + j;
        const int s0 = ebuf[b0];
        const int s1 = ebuf[j + 1 < cnt ? b0 + 1 : b0];
        const int s2 = ebuf[j + 2 < cnt ? b0 + 2 : b0];
        const int s3 = ebuf[j + 3 < cnt ? b0 + 3 : b0];
        const float n0 = disb[s0] * ds;
        const float n1 = j + 1 < cnt ? disb[s1] * ds : 0.0f;
        const float n2 = j + 2 < cnt ? disb[s2] * ds : 0.0f;
        const float n3 = j + 3 < cnt ? disb[s3] * ds : 0.0f;
        const uint4 u0 = linv[(size_t)s0 * 16 + l16];
        const uint4 u1 = linv[(size_t)s1 * 16 + l16];
        const uint4 u2 = linv[(size_t)s2 * 16 + l16];
        const uint4 u3 = linv[(size_t)s3 * 16 + l16];
        acc8(acc, u0, n0); acc8(acc, u1, n1); acc8(acc, u2, n2); acc8(acc, u3, n3);
    }

    const float4 bb0 = ((const float4*)bias)[l16 * 2];
    const float4 bb1 = ((const float4*)bias)[l16 * 2 + 1];
    acc[0] += bb0.x; acc[1] += bb0.y; acc[2] += bb0.z; acc[3] += bb0.w;
    acc[4] += bb1.x; acc[5] += bb1.y; acc[6] += bb1.z; acc[7] += bb1.w;
#pragma unroll
    for (int k = 0; k < 8; ++k) acc[k] = acc[k] > 0.0f ? acc[k] : 0.0f;

    uint4 pz;
    pz.x = (unsigned)f2bf(acc[0]) | ((unsigned)f2bf(acc[1]) << 16);
    pz.y = (unsigned)f2bf(acc[2]) | ((unsigned)f2bf(acc[3]) << 16);
    pz.z = (unsigned)f2bf(acc[4]) | ((unsigned)f2bf(acc[5]) << 16);
    pz.w = (unsigned)f2bf(acc[6]) | ((unsigned)f2bf(acc[7]) << 16);
    ((uint4*)outb)[(size_t)node * 16 + l16] = pz;
}

// ---------- gather conv (64-d): 8 lanes/node, uint4 rows, 8 nodes/wave ----------
__global__ __launch_bounds__(256) void gather_out_64_v2(
        const unsigned short* __restrict__ lin0, const unsigned short* __restrict__ lin1,
        const int* __restrict__ off, const int* __restrict__ degc,
        const int* __restrict__ ebuf, const float* __restrict__ dis,
        const float* __restrict__ bias,
        float* __restrict__ out0, float* __restrict__ out1,
        unsigned short* __restrict__ zb0, unsigned short* __restrict__ zb1, int n) {
    const int net = blockIdx.y;
    const unsigned short* __restrict__ lin = net ? lin1 : lin0;
    float* __restrict__ outp = net ? out1 : out0;
    unsigned short* __restrict__ zb = net ? zb1 : zb0;

    const int wave = threadIdx.x >> 6;
    const int lane = threadIdx.x & 63;
    const int grp  = lane >> 3;          // 8 node-groups per wave
    const int l8   = lane & 7;           // 8 lanes x uint4(16B) = 128B row
    const int node = blockIdx.x * 32 + wave * 8 + grp;
    if (node >= n) return;

    const float* __restrict__ disb = dis + net * n;
    const int*   __restrict__ offb = off + net * n;
    const int*   __restrict__ degb = degc + net * n;

    const float ds  = disb[node];
    const float inv = ds * ds;
    const uint4* __restrict__ linv = (const uint4*)lin;   // row stride: 8 uint4

    float acc[8];
    {
        const uint4 su = linv[(size_t)node * 8 + l8];
        const float2 p0 = bfp2f(su.x), p1 = bfp2f(su.y), p2 = bfp2f(su.z), p3 = bfp2f(su.w);
        acc[0] = p0.x * inv; acc[1] = p0.y * inv;
        acc[2] = p1.x * inv; acc[3] = p1.y * inv;
        acc[4] = p2.x * inv; acc[5] = p2.y * inv;
        acc[6] = p3.x * inv; acc[7] = p3.y * inv;
    }

    const int start = offb[node];
    const int cnt   = degb[node];
    for (int j = 0; j < cnt; j += 4) {
        const int b0 = start + j;
        const int s0 = ebuf[b0];
        const int s1 = ebuf[j + 1 < cnt ? b0 + 1 : b0];
        const int s2 = ebuf[j + 2 < cnt ? b0 + 2 : b0];
        const int s3 = ebuf[j + 3 < cnt ? b0 + 3 : b0];
        const float n0 = disb[s0] * ds;
        const float n1 = j + 1 < cnt ? disb[s1] * ds : 0.0f;
        const float n2 = j + 2 < cnt ? disb[s2] * ds : 0.0f;
        const float n3 = j + 3 < cnt ? disb[s3] * ds : 0.0f;
        const uint4 u0 = linv[(size_t)s0 * 8 + l8];
        const uint4 u1 = linv[(size_t)s1 * 8 + l8];
        const uint4 u2 = linv[(size_t)s2 * 8 + l8];
        const uint4 u3 = linv[(size_t)s3 * 8 + l8];
        acc8(acc, u0, n0); acc8(acc, u1, n1); acc8(acc, u2, n2); acc8(acc, u3, n3);
    }

    const float4 bb0 = ((const float4*)bias)[l8 * 2];
    const float4 bb1 = ((const float4*)bias)[l8 * 2 + 1];
    const float z0 = acc[0] + bb0.x, z1 = acc[1] + bb0.y, z2 = acc[2] + bb0.z, z3 = acc[3] + bb0.w;
    const float z4 = acc[4] + bb1.x, z5 = acc[5] + bb1.y, z6 = acc[6] + bb1.z, z7 = acc[7] + bb1.w;

    float4 w0; w0.x = z0; w0.y = z1; w0.z = z2; w0.w = z3;
    float4 w1; w1.x = z4; w1.y = z5; w1.z = z6; w1.w = z7;
    ((float4*)outp)[(size_t)node * 16 + l8 * 2]     = w0;
    ((float4*)outp)[(size_t)node * 16 + l8 * 2 + 1] = w1;

    uint4 pz;
    pz.x = (unsigned)f2bf(z0) | ((unsigned)f2bf(z1) << 16);
    pz.y = (unsigned)f2bf(z2) | ((unsigned)f2bf(z3) << 16);
    pz.z = (unsigned)f2bf(z4) | ((unsigned)f2bf(z5) << 16);
    pz.w = (unsigned)f2bf(z6) | ((unsigned)f2bf(z7) << 16);
    ((uint4*)zb)[(size_t)node * 8 + l8] = pz;
}

// ---------- decoder (bf16 z): p[e] = sigmoid(dot(Z[src], Z[dst])), both nets ----------
__global__ __launch_bounds__(256) void decoder2(
        const unsigned short* __restrict__ Zb0, const unsigned short* __restrict__ Zb1,
        const int* __restrict__ s_ei, const int* __restrict__ t_ei,
        float* __restrict__ out0, float* __restrict__ out1) {
    const int net = blockIdx.y;
    const unsigned short* __restrict__ Zb = net ? Zb1 : Zb0;
    const int* __restrict__ ei = net ? t_ei : s_ei;
    float* __restrict__ op = net ? out1 : out0;

    const int tid  = blockIdx.x * blockDim.x + threadIdx.x;
    const int edge = tid >> 3;   // 8 lanes per edge
    const int lane = tid & 7;
    if (edge >= N_EDGES) return;
    const int s = ei[edge], d = ei[N_EDGES + edge];
    const uint4 ua = *(const uint4*)&Zb[(size_t)s * OUT_D + lane * 8];
    const uint4 ub = *(const uint4*)&Zb[(size_t)d * OUT_D + lane * 8];
    float p = 0.0f;
    {
        const float2 a0 = bfp2f(ua.x), b0 = bfp2f(ub.x);
        const float2 a1 = bfp2f(ua.y), b1 = bfp2f(ub.y);
        const float2 a2 = bfp2f(ua.z), b2 = bfp2f(ub.z);
        const float2 a3 = bfp2f(ua.w), b3 = bfp2f(ub.w);
        p = fmaf(a0.x, b0.x, p); p = fmaf(a0.y, b0.y, p);
        p = fmaf(a1.x, b1.x, p); p = fmaf(a1.y, b1.y, p);
        p = fmaf(a2.x, b2.x, p); p = fmaf(a2.y, b2.y, p);
        p = fmaf(a3.x, b3.x, p); p = fmaf(a3.y, b3.y, p);
    }
    p += __shfl_down(p, 4, 8);
    p += __shfl_down(p, 2, 8);
    p += __shfl_down(p, 1, 8);
    if (lane == 0) op[edge] = 1.0f / (1.0f + expf(-p));
}

extern "C" void kernel_launch(void* const* d_in, const int* in_sizes, int n_in,
                              void* d_out, int out_size, void* d_ws, size_t ws_size,
                              hipStream_t stream) {
    const float* xs  = (const float*)d_in[0];
    const float* xt  = (const float*)d_in[1];
    const int* s_ei  = (const int*)d_in[2];
    const int* t_ei  = (const int*)d_in[3];
    const float* W1  = (const float*)d_in[4];
    const float* b1  = (const float*)d_in[5];
    const float* W2  = (const float*)d_in[6];
    const float* b2  = (const float*)d_in[7];
    const float* W3  = (const float*)d_in[8];
    const float* b3  = (const float*)d_in[9];

    // workspace layout (~110 MB): 4 big bf16 feature buffers + CSR (concat 2N/2E)
    unsigned short* Lb1 = (unsigned short*)d_ws;                 // NPAD*128 bf16 (lin conv1, net s)
    unsigned short* Lb2 = Lb1 + (size_t)N_PAD * HID;             // NPAD*128 bf16 (lin conv1, net t)
    unsigned short* Hb1 = Lb2 + (size_t)N_PAD * HID;             // NPAD*128 bf16 (h, net s)
    unsigned short* Hb2 = Hb1 + (size_t)N_PAD * HID;             // NPAD*128 bf16 (h, net t)
    // aliases (lifetime-disjoint): conv3 lin overlays conv1 lin; z overlays h
    unsigned short* L2b1 = Lb1;                                  // NPAD*64 bf16 (lin conv3, s)
    unsigned short* L2b2 = Lb2;
    unsigned short* Zb1  = Hb1;                                  // NPAD*64 bf16 (z copy, s)
    unsigned short* Zb2  = Hb2;
    unsigned short* Wp1 = Hb2 + (size_t)N_PAD * HID;             // 128*128 bf16
    unsigned short* Wp2 = Wp1 + 128 * HID;                       // 128*128 bf16
    unsigned short* W3p = Wp2 + 128 * HID;                       // 128*64 bf16
    float* dis          = (float*)(W3p + 128 * OUT_D);           // 2N f
    int*   deg          = (int*)(dis + TOTN);                    // 2N i
    int*   off          = deg + TOTN;                            // 2N i
    int*   cur          = off + TOTN;                            // 2N i
    int*   partial      = cur + TOTN;                            // 256 i
    int*   ebuf         = partial + 256;                         // 2E i

    float* out = (float*)d_out;
    float* out_zs = out;                                 // N*64
    float* out_zt = out + (size_t)N_NODES * OUT_D;       // N*64
    float* out_ps = out + 2 * (size_t)N_NODES * OUT_D;   // E
    float* out_pt = out_ps + N_EDGES;                    // E

    // ---- CSR build, both networks in one concatenated pass ----
    hipMemsetAsync(deg, 0, (size_t)TOTN * sizeof(int), stream);
    deg_count2<<<(2 * N_EDGES + 255) / 256, 256, 0, stream>>>(s_ei, t_ei, deg);
    scan_block_sums<<<NBLK_SCAN, SCAN_BLK, 0, stream>>>(deg, partial, TOTN);
    scan_partials<<<1, SCAN_BLK, 0, stream>>>(partial, NBLK_SCAN);
    scan_final<<<NBLK_SCAN, SCAN_BLK, 0, stream>>>(deg, partial, off, cur, dis, TOTN);
    bucket2<<<(2 * N_EDGES + 255) / 256, 256, 0, stream>>>(s_ei, t_ei, cur, ebuf);

    // ---- weights (one tiny launch) ----
    pack_all<<<(2 * 128 * HID + 128 * OUT_D + 255) / 256, 256, 0, stream>>>(
        W1, W2, W3, Wp1, Wp2, W3p);

    // ---- conv1/conv2 lin: fused fp32->bf16 convert + MFMA GEMM, both nets ----
    mfma_gemm_f32<HID><<<dim3(ROW_BLKS, 2), 256, 0, stream>>>(
        xs, xt, Wp1, Wp2, Lb1, Lb2, N_NODES);

    // ---- gather + bias + relu, both nets ----
    gather_relu_128_v2<<<dim3((N_NODES + 15) / 16, 2), 256, 0, stream>>>(
        Lb1, Lb2, off, deg, ebuf, dis, b1, b2, Hb1, Hb2, N_NODES);

    // ---- conv3 lin: MFMA GEMM (bf16 in), both nets ----
    mfma_gemm_bf<OUT_D><<<dim3(ROW_BLKS, 2), 256, 0, stream>>>(
        Hb1, Hb2, W3p, L2b1, L2b2, N_NODES);

    // ---- gather -> z (fp32 out) + bf16 copy, both nets ----
    gather_out_64_v2<<<dim3((N_NODES + 31) / 32, 2), 256, 0, stream>>>(
        L2b1, L2b2, off, deg, ebuf, dis, b3, out_zs, out_zt, Zb1, Zb2, N_NODES);

    // ---- decoder, both nets ----
    decoder2<<<dim3((int)(((size_t)N_EDGES * 8 + 255) / 256), 2), 256, 0, stream>>>(
        Zb1, Zb2, s_ei, t_ei, out_ps, out_pt);
}

// Round 2
// 356.168 us; speedup vs baseline: 1.5025x; 1.2436x over previous
//
#include <hip/hip_runtime.h>

// Problem constants (match reference)
constexpr int N_NODES = 100000;
constexpr int N_EDGES = 500000;
constexpr int HID     = 128;   // conv1/conv2 output dim
constexpr int OUT_D   = 64;    // conv3 output dim
constexpr int TOTN    = 2 * N_NODES;   // both networks concatenated

constexpr int ROW_BLKS = (N_NODES + 63) / 64;   // 1563 blocks of 64 rows
constexpr int N_PAD    = ROW_BLKS * 64;          // 100032 padded rows

// ---- CSR build via coarse bucket binning ----
constexpr int BK_LG    = 10;                      // 1024 nodes per bucket
constexpr int BK_W     = 1 << BK_LG;
constexpr int NBUCK    = (TOTN + BK_W - 1) >> BK_LG;   // 196
constexpr int BCAP     = 12288;                   // 2.4x mean (5120); overflow ~ impossible
constexpr int BIN_TILE = 4096;                    // edges per bin block
constexpr int BIN_NBLK = (2 * N_EDGES + BIN_TILE - 1) / BIN_TILE;  // 245
static_assert(NBUCK <= 256, "bucket scan must fit one block");

typedef __attribute__((ext_vector_type(8))) short short8;
typedef __attribute__((ext_vector_type(4))) float float4v;

// float -> bf16 (round-to-nearest-even), as raw ushort
__device__ __forceinline__ unsigned short f2bf(float f) {
    unsigned u = __float_as_uint(f);
    u += 0x7fffu + ((u >> 16) & 1u);
    return (unsigned short)(u >> 16);
}
// packed pair of bf16 (lo = even col, hi = odd col) -> two floats
__device__ __forceinline__ float2 bfp2f(unsigned u) {
    float2 r;
    r.x = __uint_as_float(u << 16);
    r.y = __uint_as_float(u & 0xffff0000u);
    return r;
}

// 8 bf16 (one uint4) scaled-accumulate into acc[0..7] (static indices only)
__device__ __forceinline__ void acc8(float* acc, uint4 u, float nm) {
    const float2 p0 = bfp2f(u.x), p1 = bfp2f(u.y), p2 = bfp2f(u.z), p3 = bfp2f(u.w);
    acc[0] = fmaf(p0.x, nm, acc[0]); acc[1] = fmaf(p0.y, nm, acc[1]);
    acc[2] = fmaf(p1.x, nm, acc[2]); acc[3] = fmaf(p1.y, nm, acc[3]);
    acc[4] = fmaf(p2.x, nm, acc[4]); acc[5] = fmaf(p2.y, nm, acc[5]);
    acc[6] = fmaf(p3.x, nm, acc[6]); acc[7] = fmaf(p3.y, nm, acc[7]);
}

// ---------- P1: bin edges into 196 coarse buckets (contiguous run writes) ----------
__global__ __launch_bounds__(256) void bin_edges(const int* __restrict__ s_ei,
                                                 const int* __restrict__ t_ei,
                                                 int* __restrict__ tail,
                                                 uint2* __restrict__ binned) {
    __shared__ int hist[NBUCK];
    __shared__ int lcur[NBUCK];
    for (int i = threadIdx.x; i < NBUCK; i += 256) hist[i] = 0;
    __syncthreads();

    const int base_e = blockIdx.x * BIN_TILE;
    int esrc[16], egd[16], ebk[16];
#pragma unroll
    for (int k = 0; k < 16; ++k) {
        const int e = base_e + k * 256 + threadIdx.x;
        int s = 0, g = -1;
        if (e < N_EDGES) {
            s = s_ei[e];
            g = s_ei[N_EDGES + e];
        } else if (e < 2 * N_EDGES) {
            const int j = e - N_EDGES;
            s = t_ei[j];
            g = N_NODES + t_ei[N_EDGES + j];
        }
        esrc[k] = s; egd[k] = g;
        if (g >= 0) { ebk[k] = g >> BK_LG; atomicAdd(&hist[ebk[k]], 1); }
        else ebk[k] = -1;
    }
    __syncthreads();
    // reserve one contiguous range per (block, bucket)
    for (int i = threadIdx.x; i < NBUCK; i += 256) {
        const int h = hist[i];
        lcur[i] = h ? atomicAdd(&tail[i], h) : 0;
    }
    __syncthreads();
#pragma unroll
    for (int k = 0; k < 16; ++k) {
        if (ebk[k] >= 0) {
            const int p = atomicAdd(&lcur[ebk[k]], 1);     // LDS atomic -> global pos
            if (p < BCAP)
                binned[(size_t)ebk[k] * BCAP + p] = make_uint2((unsigned)esrc[k], (unsigned)egd[k]);
        }
    }
}

// ---------- P1.5: exclusive scan of bucket counts -> CSR bucket bases ----------
__global__ void scan_tail(const int* __restrict__ tail, int* __restrict__ bbase) {
    __shared__ int s[256];
    const int t = threadIdx.x;
    const int v = (t < NBUCK) ? min(tail[t], BCAP) : 0;
    s[t] = v;
    __syncthreads();
    for (int o = 1; o < 256; o <<= 1) {
        const int x = (t >= o) ? s[t - o] : 0;
        __syncthreads();
        if (t >= o) s[t] += x;
        __syncthreads();
    }
    if (t < NBUCK) bbase[t] = s[t] - v;   // exclusive
}

// ---------- P2: per-bucket CSR build (block-local scatter window) ----------
__global__ __launch_bounds__(256) void build_csr(const int* __restrict__ tail,
                                                 const int* __restrict__ bbase,
                                                 const uint2* __restrict__ binned,
                                                 int* __restrict__ off, int* __restrict__ deg,
                                                 float* __restrict__ dis, int* __restrict__ ebuf) {
    __shared__ int hist[BK_W];
    __shared__ int ssum[256];
    const int b   = blockIdx.x;
    const int t   = threadIdx.x;
    const int gn0 = b << BK_LG;
    const int nn  = min(BK_W, TOTN - gn0);
    const int cnt = min(tail[b], BCAP);
    const int cbase = bbase[b];
    const uint2* __restrict__ mine = binned + (size_t)b * BCAP;

    for (int i = t; i < BK_W; i += 256) hist[i] = 0;
    __syncthreads();
    for (int r = t; r < cnt; r += 256)
        atomicAdd(&hist[(int)mine[r].y - gn0], 1);
    __syncthreads();

    // exclusive scan over 1024 histogram entries (4 per thread)
    const int h0 = hist[t * 4 + 0], h1 = hist[t * 4 + 1];
    const int h2 = hist[t * 4 + 2], h3 = hist[t * 4 + 3];
    const int ts = h0 + h1 + h2 + h3;
    ssum[t] = ts;
    __syncthreads();
    for (int o = 1; o < 256; o <<= 1) {
        const int x = (t >= o) ? ssum[t - o] : 0;
        __syncthreads();
        if (t >= o) ssum[t] += x;
        __syncthreads();
    }
    const int ex = ssum[t] - ts;
    const int o0 = ex, o1 = ex + h0, o2 = o1 + h1, o3 = o2 + h2;

    // node outputs (coalesced)
    if (t * 4 + 0 < nn) { const int g = gn0 + t * 4 + 0; off[g] = cbase + o0; deg[g] = h0; dis[g] = rsqrtf((float)h0 + 1.0f); }
    if (t * 4 + 1 < nn) { const int g = gn0 + t * 4 + 1; off[g] = cbase + o1; deg[g] = h1; dis[g] = rsqrtf((float)h1 + 1.0f); }
    if (t * 4 + 2 < nn) { const int g = gn0 + t * 4 + 2; off[g] = cbase + o2; deg[g] = h2; dis[g] = rsqrtf((float)h2 + 1.0f); }
    if (t * 4 + 3 < nn) { const int g = gn0 + t * 4 + 3; off[g] = cbase + o3; dis[g] = rsqrtf((float)h3 + 1.0f); deg[g] = h3; }
    __syncthreads();

    // repurpose hist as running cursors (exclusive offsets)
    hist[t * 4 + 0] = o0; hist[t * 4 + 1] = o1; hist[t * 4 + 2] = o2; hist[t * 4 + 3] = o3;
    __syncthreads();

    // scatter into block-local CSR window (~20 KB -> single XCD L2)
    for (int r = t; r < cnt; r += 256) {
        const uint2 rec = mine[r];
        const int p = atomicAdd(&hist[(int)rec.y - gn0], 1);
        ebuf[cbase + p] = (int)rec.x;
    }
}

// ---------- pack all weights into MFMA B-fragment order, bf16, one launch ----------
__device__ __forceinline__ void pack_one(const float* __restrict__ W,
                                         unsigned short* __restrict__ Wp,
                                         int t, int COLS, int lg) {
    const int k = t >> lg, nn = t & (COLS - 1);
    const int kb = k >> 5, rem = k & 31, quad = rem >> 3, j = rem & 7;
    Wp[((size_t)(kb * 4 + quad) * COLS + nn) * 8 + j] = f2bf(W[t]);
}

__global__ void pack_all(const float* __restrict__ W1, const float* __restrict__ W2,
                         const float* __restrict__ W3,
                         unsigned short* __restrict__ Wp1, unsigned short* __restrict__ Wp2,
                         unsigned short* __restrict__ W3p) {
    const int idx = blockIdx.x * blockDim.x + threadIdx.x;
    if (idx < 128 * HID) {
        pack_one(W1, Wp1, idx, HID, 7);
    } else if (idx < 2 * 128 * HID) {
        pack_one(W2, Wp2, idx - 128 * HID, HID, 7);
    } else if (idx < 2 * 128 * HID + 128 * OUT_D) {
        pack_one(W3, W3p, idx - 2 * 128 * HID, OUT_D, 6);
    }
}

// ---------- MFMA GEMM with fused fp32->bf16 convert of A (both nets) ----------
template <int COLS>
__global__ __launch_bounds__(256) void mfma_gemm_f32(const float* __restrict__ X0,
                                                     const float* __restrict__ X1,
                                                     const unsigned short* __restrict__ Wp0,
                                                     const unsigned short* __restrict__ Wp1,
                                                     unsigned short* __restrict__ Y0,
                                                     unsigned short* __restrict__ Y1, int n) {
    const float* __restrict__ X = blockIdx.y ? X1 : X0;
    const unsigned short* __restrict__ Wp = blockIdx.y ? Wp1 : Wp0;
    unsigned short* __restrict__ Y = blockIdx.y ? Y1 : Y0;

    const int wave = threadIdx.x >> 6;
    const int lane = threadIdx.x & 63;
    const int quad = lane >> 4;
    const int l16  = lane & 15;
    const int rowbase = blockIdx.x * 64 + wave * 16;
    const int row = rowbase + l16;
    const int rc  = row < n ? row : n - 1;    // clamp: garbage rows never stored

    short8 a[4];
    const size_t arow = (size_t)rc * 128;
#pragma unroll
    for (int kb = 0; kb < 4; ++kb) {
        const float4 f0 = *(const float4*)&X[arow + kb * 32 + quad * 8];
        const float4 f1 = *(const float4*)&X[arow + kb * 32 + quad * 8 + 4];
        short8 v;
        v[0] = (short)f2bf(f0.x); v[1] = (short)f2bf(f0.y);
        v[2] = (short)f2bf(f0.z); v[3] = (short)f2bf(f0.w);
        v[4] = (short)f2bf(f1.x); v[5] = (short)f2bf(f1.y);
        v[6] = (short)f2bf(f1.z); v[7] = (short)f2bf(f1.w);
        a[kb] = v;
    }

#pragma unroll
    for (int ct = 0; ct < COLS / 16; ++ct) {
        const int col = ct * 16 + l16;
        float4v acc = {0.0f, 0.0f, 0.0f, 0.0f};
#pragma unroll
        for (int kb = 0; kb < 4; ++kb) {
            const short8 b = *(const short8*)&Wp[((size_t)(kb * 4 + quad) * COLS + col) * 8];
            acc = __builtin_amdgcn_mfma_f32_16x16x32_bf16(a[kb], b, acc, 0, 0, 0);
        }
#pragma unroll
        for (int r = 0; r < 4; ++r) {
            const int orow = rowbase + quad * 4 + r;   // C/D: row=(lane>>4)*4+reg, col=lane&15
            if (orow < n) Y[(size_t)orow * COLS + col] = f2bf(acc[r]);
        }
    }
}

// ---------- MFMA GEMM, bf16 input (conv3), both nets ----------
template <int COLS>
__global__ __launch_bounds__(256) void mfma_gemm_bf(const unsigned short* __restrict__ Xb0,
                                                    const unsigned short* __restrict__ Xb1,
                                                    const unsigned short* __restrict__ Wp,
                                                    unsigned short* __restrict__ Y0,
                                                    unsigned short* __restrict__ Y1, int n) {
    const unsigned short* __restrict__ Xb = blockIdx.y ? Xb1 : Xb0;
    unsigned short* __restrict__ Y = blockIdx.y ? Y1 : Y0;

    const int wave = threadIdx.x >> 6;
    const int lane = threadIdx.x & 63;
    const int quad = lane >> 4;
    const int l16  = lane & 15;
    const int rowbase = blockIdx.x * 64 + wave * 16;

    short8 a[4];
    const size_t arow = (size_t)(rowbase + l16) * 128;
#pragma unroll
    for (int kb = 0; kb < 4; ++kb)
        a[kb] = *(const short8*)&Xb[arow + kb * 32 + quad * 8];

#pragma unroll
    for (int ct = 0; ct < COLS / 16; ++ct) {
        const int col = ct * 16 + l16;
        float4v acc = {0.0f, 0.0f, 0.0f, 0.0f};
#pragma unroll
        for (int kb = 0; kb < 4; ++kb) {
            const short8 b = *(const short8*)&Wp[((size_t)(kb * 4 + quad) * COLS + col) * 8];
            acc = __builtin_amdgcn_mfma_f32_16x16x32_bf16(a[kb], b, acc, 0, 0, 0);
        }
#pragma unroll
        for (int r = 0; r < 4; ++r) {
            const int row = rowbase + quad * 4 + r;
            if (row < n) Y[(size_t)row * COLS + col] = f2bf(acc[r]);
        }
    }
}

// ---------- gather conv (128-d): 16 lanes/node, uint4 rows, 4 nodes/wave ----------
__global__ __launch_bounds__(256) void gather_relu_128_v2(
        const unsigned short* __restrict__ lin0, const unsigned short* __restrict__ lin1,
        const int* __restrict__ off, const int* __restrict__ degc,
        const int* __restrict__ ebuf, const float* __restrict__ dis,
        const float* __restrict__ bias0, const float* __restrict__ bias1,
        unsigned short* __restrict__ out0, unsigned short* __restrict__ out1, int n) {
    const int net = blockIdx.y;
    const unsigned short* __restrict__ lin = net ? lin1 : lin0;
    unsigned short* __restrict__ outb = net ? out1 : out0;
    const float* __restrict__ bias = net ? bias1 : bias0;

    const int wave = threadIdx.x >> 6;
    const int lane = threadIdx.x & 63;
    const int grp  = lane >> 4;          // 4 node-groups per wave
    const int l16  = lane & 15;          // 16 lanes x uint4(16B) = 256B row
    const int node = blockIdx.x * 16 + wave * 4 + grp;
    if (node >= n) return;

    const float* __restrict__ disb = dis + net * n;
    const int*   __restrict__ offb = off + net * n;
    const int*   __restrict__ degb = degc + net * n;

    const float ds  = disb[node];
    const float inv = ds * ds;                 // 1/(deg+1)
    const uint4* __restrict__ linv = (const uint4*)lin;   // row stride: 16 uint4

    float acc[8];
    {
        const uint4 su = linv[(size_t)node * 16 + l16];
        const float2 p0 = bfp2f(su.x), p1 = bfp2f(su.y), p2 = bfp2f(su.z), p3 = bfp2f(su.w);
        acc[0] = p0.x * inv; acc[1] = p0.y * inv;
        acc[2] = p1.x * inv; acc[3] = p1.y * inv;
        acc[4] = p2.x * inv; acc[5] = p2.y * inv;
        acc[6] = p3.x * inv; acc[7] = p3.y * inv;
    }

    const int start = offb[node];
    const int cnt   = degb[node];
    for (int j = 0; j < cnt; j += 4) {         // masked batches: no serial tail
        const int b0 = start + j;
        const int s0 = ebuf[b0];
        const int s1 = ebuf[j + 1 < cnt ? b0 + 1 : b0];
        const int s2 = ebuf[j + 2 < cnt ? b0 + 2 : b0];
        const int s3 = ebuf[j + 3 < cnt ? b0 + 3 : b0];
        const float n0 = disb[s0] * ds;
        const float n1 = j + 1 < cnt ? disb[s1] * ds : 0.0f;
        const float n2 = j + 2 < cnt ? disb[s2] * ds : 0.0f;
        const float n3 = j + 3 < cnt ? disb[s3] * ds : 0.0f;
        const uint4 u0 = linv[(size_t)s0 * 16 + l16];
        const uint4 u1 = linv[(size_t)s1 * 16 + l16];
        const uint4 u2 = linv[(size_t)s2 * 16 + l16];
        const uint4 u3 = linv[(size_t)s3 * 16 + l16];
        acc8(acc, u0, n0); acc8(acc, u1, n1); acc8(acc, u2, n2); acc8(acc, u3, n3);
    }

    const float4 bb0 = ((const float4*)bias)[l16 * 2];
    const float4 bb1 = ((const float4*)bias)[l16 * 2 + 1];
    acc[0] += bb0.x; acc[1] += bb0.y; acc[2] += bb0.z; acc[3] += bb0.w;
    acc[4] += bb1.x; acc[5] += bb1.y; acc[6] += bb1.z; acc[7] += bb1.w;
#pragma unroll
    for (int k = 0; k < 8; ++k) acc[k] = acc[k] > 0.0f ? acc[k] : 0.0f;

    uint4 pz;
    pz.x = (unsigned)f2bf(acc[0]) | ((unsigned)f2bf(acc[1]) << 16);
    pz.y = (unsigned)f2bf(acc[2]) | ((unsigned)f2bf(acc[3]) << 16);
    pz.z = (unsigned)f2bf(acc[4]) | ((unsigned)f2bf(acc[5]) << 16);
    pz.w = (unsigned)f2bf(acc[6]) | ((unsigned)f2bf(acc[7]) << 16);
    ((uint4*)outb)[(size_t)node * 16 + l16] = pz;
}

// ---------- gather conv (64-d): 8 lanes/node, uint4 rows, 8 nodes/wave ----------
__global__ __launch_bounds__(256) void gather_out_64_v2(
        const unsigned short* __restrict__ lin0, const unsigned short* __restrict__ lin1,
        const int* __restrict__ off, const int* __restrict__ degc,
        const int* __restrict__ ebuf, const float* __restrict__ dis,
        const float* __restrict__ bias,
        float* __restrict__ out0, float* __restrict__ out1,
        unsigned short* __restrict__ zb0, unsigned short* __restrict__ zb1, int n) {
    const int net = blockIdx.y;
    const unsigned short* __restrict__ lin = net ? lin1 : lin0;
    float* __restrict__ outp = net ? out1 : out0;
    unsigned short* __restrict__ zb = net ? zb1 : zb0;

    const int wave = threadIdx.x >> 6;
    const int lane = threadIdx.x & 63;
    const int grp  = lane >> 3;          // 8 node-groups per wave
    const int l8   = lane & 7;           // 8 lanes x uint4(16B) = 128B row
    const int node = blockIdx.x * 32 + wave * 8 + grp;
    if (node >= n) return;

    const float* __restrict__ disb = dis + net * n;
    const int*   __restrict__ offb = off + net * n;
    const int*   __restrict__ degb = degc + net * n;

    const float ds  = disb[node];
    const float inv = ds * ds;
    const uint4* __restrict__ linv = (const uint4*)lin;   // row stride: 8 uint4

    float acc[8];
    {
        const uint4 su = linv[(size_t)node * 8 + l8];
        const float2 p0 = bfp2f(su.x), p1 = bfp2f(su.y), p2 = bfp2f(su.z), p3 = bfp2f(su.w);
        acc[0] = p0.x * inv; acc[1] = p0.y * inv;
        acc[2] = p1.x * inv; acc[3] = p1.y * inv;
        acc[4] = p2.x * inv; acc[5] = p2.y * inv;
        acc[6] = p3.x * inv; acc[7] = p3.y * inv;
    }

    const int start = offb[node];
    const int cnt   = degb[node];
    for (int j = 0; j < cnt; j += 4) {
        const int b0 = start + j;
        const int s0 = ebuf[b0];
        const int s1 = ebuf[j + 1 < cnt ? b0 + 1 : b0];
        const int s2 = ebuf[j + 2 < cnt ? b0 + 2 : b0];
        const int s3 = ebuf[j + 3 < cnt ? b0 + 3 : b0];
        const float n0 = disb[s0] * ds;
        const float n1 = j + 1 < cnt ? disb[s1] * ds : 0.0f;
        const float n2 = j + 2 < cnt ? disb[s2] * ds : 0.0f;
        const float n3 = j + 3 < cnt ? disb[s3] * ds : 0.0f;
        const uint4 u0 = linv[(size_t)s0 * 8 + l8];
        const uint4 u1 = linv[(size_t)s1 * 8 + l8];
        const uint4 u2 = linv[(size_t)s2 * 8 + l8];
        const uint4 u3 = linv[(size_t)s3 * 8 + l8];
        acc8(acc, u0, n0); acc8(acc, u1, n1); acc8(acc, u2, n2); acc8(acc, u3, n3);
    }

    const float4 bb0 = ((const float4*)bias)[l8 * 2];
    const float4 bb1 = ((const float4*)bias)[l8 * 2 + 1];
    const float z0 = acc[0] + bb0.x, z1 = acc[1] + bb0.y, z2 = acc[2] + bb0.z, z3 = acc[3] + bb0.w;
    const float z4 = acc[4] + bb1.x, z5 = acc[5] + bb1.y, z6 = acc[6] + bb1.z, z7 = acc[7] + bb1.w;

    float4 w0; w0.x = z0; w0.y = z1; w0.z = z2; w0.w = z3;
    float4 w1; w1.x = z4; w1.y = z5; w1.z = z6; w1.w = z7;
    ((float4*)outp)[(size_t)node * 16 + l8 * 2]     = w0;
    ((float4*)outp)[(size_t)node * 16 + l8 * 2 + 1] = w1;

    uint4 pz;
    pz.x = (unsigned)f2bf(z0) | ((unsigned)f2bf(z1) << 16);
    pz.y = (unsigned)f2bf(z2) | ((unsigned)f2bf(z3) << 16);
    pz.z = (unsigned)f2bf(z4) | ((unsigned)f2bf(z5) << 16);
    pz.w = (unsigned)f2bf(z6) | ((unsigned)f2bf(z7) << 16);
    ((uint4*)zb)[(size_t)node * 8 + l8] = pz;
}

// ---------- decoder (bf16 z): p[e] = sigmoid(dot(Z[src], Z[dst])), both nets ----------
__global__ __launch_bounds__(256) void decoder2(
        const unsigned short* __restrict__ Zb0, const unsigned short* __restrict__ Zb1,
        const int* __restrict__ s_ei, const int* __restrict__ t_ei,
        float* __restrict__ out0, float* __restrict__ out1) {
    const int net = blockIdx.y;
    const unsigned short* __restrict__ Zb = net ? Zb1 : Zb0;
    const int* __restrict__ ei = net ? t_ei : s_ei;
    float* __restrict__ op = net ? out1 : out0;

    const int tid  = blockIdx.x * blockDim.x + threadIdx.x;
    const int edge = tid >> 3;   // 8 lanes per edge
    const int lane = tid & 7;
    if (edge >= N_EDGES) return;
    const int s = ei[edge], d = ei[N_EDGES + edge];
    const uint4 ua = *(const uint4*)&Zb[(size_t)s * OUT_D + lane * 8];
    const uint4 ub = *(const uint4*)&Zb[(size_t)d * OUT_D + lane * 8];
    float p = 0.0f;
    {
        const float2 a0 = bfp2f(ua.x), b0 = bfp2f(ub.x);
        const float2 a1 = bfp2f(ua.y), b1 = bfp2f(ub.y);
        const float2 a2 = bfp2f(ua.z), b2 = bfp2f(ub.z);
        const float2 a3 = bfp2f(ua.w), b3 = bfp2f(ub.w);
        p = fmaf(a0.x, b0.x, p); p = fmaf(a0.y, b0.y, p);
        p = fmaf(a1.x, b1.x, p); p = fmaf(a1.y, b1.y, p);
        p = fmaf(a2.x, b2.x, p); p = fmaf(a2.y, b2.y, p);
        p = fmaf(a3.x, b3.x, p); p = fmaf(a3.y, b3.y, p);
    }
    p += __shfl_down(p, 4, 8);
    p += __shfl_down(p, 2, 8);
    p += __shfl_down(p, 1, 8);
    if (lane == 0) op[edge] = 1.0f / (1.0f + expf(-p));
}

extern "C" void kernel_launch(void* const* d_in, const int* in_sizes, int n_in,
                              void* d_out, int out_size, void* d_ws, size_t ws_size,
                              hipStream_t stream) {
    const float* xs  = (const float*)d_in[0];
    const float* xt  = (const float*)d_in[1];
    const int* s_ei  = (const int*)d_in[2];
    const int* t_ei  = (const int*)d_in[3];
    const float* W1  = (const float*)d_in[4];
    const float* b1  = (const float*)d_in[5];
    const float* W2  = (const float*)d_in[6];
    const float* b2  = (const float*)d_in[7];
    const float* W3  = (const float*)d_in[8];
    const float* b3  = (const float*)d_in[9];

    // workspace layout (~110 MB): 4 big bf16 feature buffers + CSR (concat 2N/2E)
    unsigned short* Lb1 = (unsigned short*)d_ws;                 // NPAD*128 bf16 (lin conv1, net s)
    unsigned short* Lb2 = Lb1 + (size_t)N_PAD * HID;             // NPAD*128 bf16 (lin conv1, net t)
    unsigned short* Hb1 = Lb2 + (size_t)N_PAD * HID;             // NPAD*128 bf16 (h, net s)
    unsigned short* Hb2 = Hb1 + (size_t)N_PAD * HID;             // NPAD*128 bf16 (h, net t)
    // aliases (lifetime-disjoint):
    //   conv3 lin overlays conv1 lin; z overlays h
    //   binned edge records overlay Hb (dead before gather_relu writes Hb)
    unsigned short* L2b1 = Lb1;                                  // NPAD*64 bf16 (lin conv3, s)
    unsigned short* L2b2 = Lb2;
    unsigned short* Zb1  = Hb1;                                  // NPAD*64 bf16 (z copy, s)
    unsigned short* Zb2  = Hb2;
    uint2* binned       = (uint2*)Hb1;                           // NBUCK*BCAP*8B = 19.3 MB
    unsigned short* Wp1 = Hb2 + (size_t)N_PAD * HID;             // 128*128 bf16
    unsigned short* Wp2 = Wp1 + 128 * HID;                       // 128*128 bf16
    unsigned short* W3p = Wp2 + 128 * HID;                       // 128*64 bf16
    float* dis          = (float*)(W3p + 128 * OUT_D);           // 2N f
    int*   deg          = (int*)(dis + TOTN);                    // 2N i
    int*   off          = deg + TOTN;                            // 2N i
    int*   ebuf         = off + TOTN;                            // 2E i
    int*   tail         = ebuf + 2 * N_EDGES;                    // NBUCK i
    int*   bbase        = tail + NBUCK;                          // NBUCK i

    float* out = (float*)d_out;
    float* out_zs = out;                                 // N*64
    float* out_zt = out + (size_t)N_NODES * OUT_D;       // N*64
    float* out_ps = out + 2 * (size_t)N_NODES * OUT_D;   // E
    float* out_pt = out_ps + N_EDGES;                    // E

    // ---- CSR build via bucket binning (replaces deg_count + 3 scans + bucket) ----
    hipMemsetAsync(tail, 0, NBUCK * sizeof(int), stream);
    bin_edges<<<BIN_NBLK, 256, 0, stream>>>(s_ei, t_ei, tail, binned);
    scan_tail<<<1, 256, 0, stream>>>(tail, bbase);
    build_csr<<<NBUCK, 256, 0, stream>>>(tail, bbase, binned, off, deg, dis, ebuf);

    // ---- weights (one tiny launch) ----
    pack_all<<<(2 * 128 * HID + 128 * OUT_D + 255) / 256, 256, 0, stream>>>(
        W1, W2, W3, Wp1, Wp2, W3p);

    // ---- conv1/conv2 lin: fused fp32->bf16 convert + MFMA GEMM, both nets ----
    mfma_gemm_f32<HID><<<dim3(ROW_BLKS, 2), 256, 0, stream>>>(
        xs, xt, Wp1, Wp2, Lb1, Lb2, N_NODES);

    // ---- gather + bias + relu, both nets ----
    gather_relu_128_v2<<<dim3((N_NODES + 15) / 16, 2), 256, 0, stream>>>(
        Lb1, Lb2, off, deg, ebuf, dis, b1, b2, Hb1, Hb2, N_NODES);

    // ---- conv3 lin: MFMA GEMM (bf16 in), both nets ----
    mfma_gemm_bf<OUT_D><<<dim3(ROW_BLKS, 2), 256, 0, stream>>>(
        Hb1, Hb2, W3p, L2b1, L2b2, N_NODES);

    // ---- gather -> z (fp32 out) + bf16 copy, both nets ----
    gather_out_64_v2<<<dim3((N_NODES + 31) / 32, 2), 256, 0, stream>>>(
        L2b1, L2b2, off, deg, ebuf, dis, b3, out_zs, out_zt, Zb1, Zb2, N_NODES);

    // ---- decoder, both nets ----
    decoder2<<<dim3((int)(((size_t)N_EDGES * 8 + 255) / 256), 2), 256, 0, stream>>>(
        Zb1, Zb2, s_ei, t_ei, out_ps, out_pt);
}

// Round 3
// 338.375 us; speedup vs baseline: 1.5815x; 1.0526x over previous
//
#include <hip/hip_runtime.h>

// Problem constants (match reference)
constexpr int N_NODES = 100000;
constexpr int N_EDGES = 500000;
constexpr int HID     = 128;   // conv1/conv2 output dim
constexpr int OUT_D   = 64;    // conv3 output dim
constexpr int TOTN    = 2 * N_NODES;   // both networks concatenated

constexpr int ROW_BLKS = (N_NODES + 63) / 64;   // 1563 blocks of 64 rows
constexpr int N_PAD    = ROW_BLKS * 64;          // 100032 padded rows

// ---- CSR build via coarse bucket binning ----
constexpr int BK_LG    = 10;                      // 1024 nodes per bucket
constexpr int BK_W     = 1 << BK_LG;
constexpr int NBUCK    = (TOTN + BK_W - 1) >> BK_LG;   // 196
constexpr int BCAP     = 12288;                   // 2.4x mean (5120); overflow ~ impossible
constexpr int BIN_TILE = 4096;                    // edges per bin block
constexpr int BIN_NBLK = (2 * N_EDGES + BIN_TILE - 1) / BIN_TILE;  // 245
static_assert(NBUCK <= 256, "bucket scan must fit one block");

typedef __attribute__((ext_vector_type(8))) short short8;
typedef __attribute__((ext_vector_type(4))) float float4v;

// float -> bf16 (round-to-nearest-even), as raw ushort
__device__ __forceinline__ unsigned short f2bf(float f) {
    unsigned u = __float_as_uint(f);
    u += 0x7fffu + ((u >> 16) & 1u);
    return (unsigned short)(u >> 16);
}
// packed pair of bf16 (lo = even col, hi = odd col) -> two floats
__device__ __forceinline__ float2 bfp2f(unsigned u) {
    float2 r;
    r.x = __uint_as_float(u << 16);
    r.y = __uint_as_float(u & 0xffff0000u);
    return r;
}

// 8 bf16 (one uint4) scaled-accumulate into acc[0..7] (static indices only)
__device__ __forceinline__ void acc8(float* acc, uint4 u, float nm) {
    const float2 p0 = bfp2f(u.x), p1 = bfp2f(u.y), p2 = bfp2f(u.z), p3 = bfp2f(u.w);
    acc[0] = fmaf(p0.x, nm, acc[0]); acc[1] = fmaf(p0.y, nm, acc[1]);
    acc[2] = fmaf(p1.x, nm, acc[2]); acc[3] = fmaf(p1.y, nm, acc[3]);
    acc[4] = fmaf(p2.x, nm, acc[4]); acc[5] = fmaf(p2.y, nm, acc[5]);
    acc[6] = fmaf(p3.x, nm, acc[6]); acc[7] = fmaf(p3.y, nm, acc[7]);
}

// ---------- P1: bin edges into 196 coarse buckets (contiguous run writes) ----------
__global__ __launch_bounds__(256) void bin_edges(const int* __restrict__ s_ei,
                                                 const int* __restrict__ t_ei,
                                                 int* __restrict__ tail,
                                                 uint2* __restrict__ binned) {
    __shared__ int hist[NBUCK];
    __shared__ int lcur[NBUCK];
    for (int i = threadIdx.x; i < NBUCK; i += 256) hist[i] = 0;
    __syncthreads();

    const int base_e = blockIdx.x * BIN_TILE;
    int esrc[16], egd[16], ebk[16];
#pragma unroll
    for (int k = 0; k < 16; ++k) {
        const int e = base_e + k * 256 + threadIdx.x;
        int s = 0, g = -1;
        if (e < N_EDGES) {
            s = s_ei[e];
            g = s_ei[N_EDGES + e];
        } else if (e < 2 * N_EDGES) {
            const int j = e - N_EDGES;
            s = t_ei[j];
            g = N_NODES + t_ei[N_EDGES + j];
        }
        esrc[k] = s; egd[k] = g;
        if (g >= 0) { ebk[k] = g >> BK_LG; atomicAdd(&hist[ebk[k]], 1); }
        else ebk[k] = -1;
    }
    __syncthreads();
    // reserve one contiguous range per (block, bucket)
    for (int i = threadIdx.x; i < NBUCK; i += 256) {
        const int h = hist[i];
        lcur[i] = h ? atomicAdd(&tail[i], h) : 0;
    }
    __syncthreads();
#pragma unroll
    for (int k = 0; k < 16; ++k) {
        if (ebk[k] >= 0) {
            const int p = atomicAdd(&lcur[ebk[k]], 1);     // LDS atomic -> global pos
            if (p < BCAP)
                binned[(size_t)ebk[k] * BCAP + p] = make_uint2((unsigned)esrc[k], (unsigned)egd[k]);
        }
    }
}

// ---------- P1.5: exclusive scan of bucket counts -> CSR bucket bases ----------
__global__ void scan_tail(const int* __restrict__ tail, int* __restrict__ bbase) {
    __shared__ int s[256];
    const int t = threadIdx.x;
    const int v = (t < NBUCK) ? min(tail[t], BCAP) : 0;
    s[t] = v;
    __syncthreads();
    for (int o = 1; o < 256; o <<= 1) {
        const int x = (t >= o) ? s[t - o] : 0;
        __syncthreads();
        if (t >= o) s[t] += x;
        __syncthreads();
    }
    if (t < NBUCK) bbase[t] = s[t] - v;   // exclusive
}

// ---------- P2: per-bucket CSR build (block-local scatter window) ----------
__global__ __launch_bounds__(256) void build_csr(const int* __restrict__ tail,
                                                 const int* __restrict__ bbase,
                                                 const uint2* __restrict__ binned,
                                                 int* __restrict__ off, int* __restrict__ deg,
                                                 float* __restrict__ dis, int* __restrict__ ebuf) {
    __shared__ int hist[BK_W];
    __shared__ int ssum[256];
    const int b   = blockIdx.x;
    const int t   = threadIdx.x;
    const int gn0 = b << BK_LG;
    const int nn  = min(BK_W, TOTN - gn0);
    const int cnt = min(tail[b], BCAP);
    const int cbase = bbase[b];
    const uint2* __restrict__ mine = binned + (size_t)b * BCAP;

    for (int i = t; i < BK_W; i += 256) hist[i] = 0;
    __syncthreads();
    for (int r = t; r < cnt; r += 256)
        atomicAdd(&hist[(int)mine[r].y - gn0], 1);
    __syncthreads();

    // exclusive scan over 1024 histogram entries (4 per thread)
    const int h0 = hist[t * 4 + 0], h1 = hist[t * 4 + 1];
    const int h2 = hist[t * 4 + 2], h3 = hist[t * 4 + 3];
    const int ts = h0 + h1 + h2 + h3;
    ssum[t] = ts;
    __syncthreads();
    for (int o = 1; o < 256; o <<= 1) {
        const int x = (t >= o) ? ssum[t - o] : 0;
        __syncthreads();
        if (t >= o) ssum[t] += x;
        __syncthreads();
    }
    const int ex = ssum[t] - ts;
    const int o0 = ex, o1 = ex + h0, o2 = o1 + h1, o3 = o2 + h2;

    // node outputs (coalesced)
    if (t * 4 + 0 < nn) { const int g = gn0 + t * 4 + 0; off[g] = cbase + o0; deg[g] = h0; dis[g] = rsqrtf((float)h0 + 1.0f); }
    if (t * 4 + 1 < nn) { const int g = gn0 + t * 4 + 1; off[g] = cbase + o1; deg[g] = h1; dis[g] = rsqrtf((float)h1 + 1.0f); }
    if (t * 4 + 2 < nn) { const int g = gn0 + t * 4 + 2; off[g] = cbase + o2; deg[g] = h2; dis[g] = rsqrtf((float)h2 + 1.0f); }
    if (t * 4 + 3 < nn) { const int g = gn0 + t * 4 + 3; off[g] = cbase + o3; dis[g] = rsqrtf((float)h3 + 1.0f); deg[g] = h3; }
    __syncthreads();

    // repurpose hist as running cursors (exclusive offsets)
    hist[t * 4 + 0] = o0; hist[t * 4 + 1] = o1; hist[t * 4 + 2] = o2; hist[t * 4 + 3] = o3;
    __syncthreads();

    // scatter into block-local CSR window (~20 KB -> single XCD L2)
    for (int r = t; r < cnt; r += 256) {
        const uint2 rec = mine[r];
        const int p = atomicAdd(&hist[(int)rec.y - gn0], 1);
        ebuf[cbase + p] = (int)rec.x;
    }
}

// ---------- pack all weights into MFMA B-fragment order, bf16, one launch ----------
__device__ __forceinline__ void pack_one(const float* __restrict__ W,
                                         unsigned short* __restrict__ Wp,
                                         int t, int COLS, int lg) {
    const int k = t >> lg, nn = t & (COLS - 1);
    const int kb = k >> 5, rem = k & 31, quad = rem >> 3, j = rem & 7;
    Wp[((size_t)(kb * 4 + quad) * COLS + nn) * 8 + j] = f2bf(W[t]);
}

__global__ void pack_all(const float* __restrict__ W1, const float* __restrict__ W2,
                         const float* __restrict__ W3,
                         unsigned short* __restrict__ Wp1, unsigned short* __restrict__ Wp2,
                         unsigned short* __restrict__ W3p) {
    const int idx = blockIdx.x * blockDim.x + threadIdx.x;
    if (idx < 128 * HID) {
        pack_one(W1, Wp1, idx, HID, 7);
    } else if (idx < 2 * 128 * HID) {
        pack_one(W2, Wp2, idx - 128 * HID, HID, 7);
    } else if (idx < 2 * 128 * HID + 128 * OUT_D) {
        pack_one(W3, W3p, idx - 2 * 128 * HID, OUT_D, 6);
    }
}

// ---------- MFMA GEMM, fp32 A with fused bf16 convert; B staged in LDS ----------
template <int COLS>
__global__ __launch_bounds__(256) void mfma_gemm_f32(const float* __restrict__ X0,
                                                     const float* __restrict__ X1,
                                                     const unsigned short* __restrict__ Wp0,
                                                     const unsigned short* __restrict__ Wp1,
                                                     unsigned short* __restrict__ Y0,
                                                     unsigned short* __restrict__ Y1, int n) {
    __shared__ unsigned short Bs[16 * COLS * 8];   // full packed W: 32 KB (128) / 16 KB (64)

    const float* __restrict__ X = blockIdx.y ? X1 : X0;
    const unsigned short* __restrict__ Wp = blockIdx.y ? Wp1 : Wp0;
    unsigned short* __restrict__ Y = blockIdx.y ? Y1 : Y0;

    const int wave = threadIdx.x >> 6;
    const int lane = threadIdx.x & 63;
    const int quad = lane >> 4;
    const int l16  = lane & 15;
    const int rowbase = blockIdx.x * 64 + wave * 16;
    const int row = rowbase + l16;
    const int rc  = row < n ? row : n - 1;    // clamp: garbage rows never stored

    // issue ALL 8 A-tile loads first (distinct regs -> 8 loads in flight)
    float4 f[8];
    const size_t arow = (size_t)rc * 128;
#pragma unroll
    for (int i = 0; i < 8; ++i)
        f[i] = *(const float4*)&X[arow + (i >> 1) * 32 + quad * 8 + (i & 1) * 4];

    // stage packed W into LDS (overlaps with A loads in flight)
    {
        const uint4* __restrict__ wsrc = (const uint4*)Wp;
        uint4* __restrict__ wdst = (uint4*)Bs;
        constexpr int CH = 16 * COLS;              // 16B chunks
#pragma unroll
        for (int i = 0; i < CH / 256; ++i)
            wdst[i * 256 + threadIdx.x] = wsrc[i * 256 + threadIdx.x];
    }
    __syncthreads();

    // convert A to bf16 fragments
    short8 a[4];
#pragma unroll
    for (int kb = 0; kb < 4; ++kb) {
        const float4 g0 = f[2 * kb], g1 = f[2 * kb + 1];
        short8 v;
        v[0] = (short)f2bf(g0.x); v[1] = (short)f2bf(g0.y);
        v[2] = (short)f2bf(g0.z); v[3] = (short)f2bf(g0.w);
        v[4] = (short)f2bf(g1.x); v[5] = (short)f2bf(g1.y);
        v[6] = (short)f2bf(g1.z); v[7] = (short)f2bf(g1.w);
        a[kb] = v;
    }

#pragma unroll
    for (int ct = 0; ct < COLS / 16; ++ct) {
        const int col = ct * 16 + l16;
        float4v acc = {0.0f, 0.0f, 0.0f, 0.0f};
#pragma unroll
        for (int kb = 0; kb < 4; ++kb) {
            const short8 b = *(const short8*)&Bs[((kb * 4 + quad) * COLS + col) * 8];
            acc = __builtin_amdgcn_mfma_f32_16x16x32_bf16(a[kb], b, acc, 0, 0, 0);
        }
#pragma unroll
        for (int r = 0; r < 4; ++r) {
            const int orow = rowbase + quad * 4 + r;   // C/D: row=(lane>>4)*4+reg, col=lane&15
            if (orow < n) Y[(size_t)orow * COLS + col] = f2bf(acc[r]);
        }
    }
}

// ---------- MFMA GEMM, bf16 input (conv3); B staged in LDS ----------
template <int COLS>
__global__ __launch_bounds__(256) void mfma_gemm_bf(const unsigned short* __restrict__ Xb0,
                                                    const unsigned short* __restrict__ Xb1,
                                                    const unsigned short* __restrict__ Wp,
                                                    unsigned short* __restrict__ Y0,
                                                    unsigned short* __restrict__ Y1, int n) {
    __shared__ unsigned short Bs[16 * COLS * 8];

    const unsigned short* __restrict__ Xb = blockIdx.y ? Xb1 : Xb0;
    unsigned short* __restrict__ Y = blockIdx.y ? Y1 : Y0;

    const int wave = threadIdx.x >> 6;
    const int lane = threadIdx.x & 63;
    const int quad = lane >> 4;
    const int l16  = lane & 15;
    const int rowbase = blockIdx.x * 64 + wave * 16;

    // issue all 4 A loads first
    short8 a[4];
    const size_t arow = (size_t)(rowbase + l16) * 128;
#pragma unroll
    for (int kb = 0; kb < 4; ++kb)
        a[kb] = *(const short8*)&Xb[arow + kb * 32 + quad * 8];

    // stage packed W into LDS
    {
        const uint4* __restrict__ wsrc = (const uint4*)Wp;
        uint4* __restrict__ wdst = (uint4*)Bs;
        constexpr int CH = 16 * COLS;
#pragma unroll
        for (int i = 0; i < CH / 256; ++i)
            wdst[i * 256 + threadIdx.x] = wsrc[i * 256 + threadIdx.x];
    }
    __syncthreads();

#pragma unroll
    for (int ct = 0; ct < COLS / 16; ++ct) {
        const int col = ct * 16 + l16;
        float4v acc = {0.0f, 0.0f, 0.0f, 0.0f};
#pragma unroll
        for (int kb = 0; kb < 4; ++kb) {
            const short8 b = *(const short8*)&Bs[((kb * 4 + quad) * COLS + col) * 8];
            acc = __builtin_amdgcn_mfma_f32_16x16x32_bf16(a[kb], b, acc, 0, 0, 0);
        }
#pragma unroll
        for (int r = 0; r < 4; ++r) {
            const int row = rowbase + quad * 4 + r;
            if (row < n) Y[(size_t)row * COLS + col] = f2bf(acc[r]);
        }
    }
}

// ---------- gather conv (128-d): 16 lanes/node, uint4 rows, 4 nodes/wave ----------
__global__ __launch_bounds__(256) void gather_relu_128_v2(
        const unsigned short* __restrict__ lin0, const unsigned short* __restrict__ lin1,
        const int* __restrict__ off, const int* __restrict__ degc,
        const int* __restrict__ ebuf, const float* __restrict__ dis,
        const float* __restrict__ bias0, const float* __restrict__ bias1,
        unsigned short* __restrict__ out0, unsigned short* __restrict__ out1, int n) {
    const int net = blockIdx.y;
    const unsigned short* __restrict__ lin = net ? lin1 : lin0;
    unsigned short* __restrict__ outb = net ? out1 : out0;
    const float* __restrict__ bias = net ? bias1 : bias0;

    const int wave = threadIdx.x >> 6;
    const int lane = threadIdx.x & 63;
    const int grp  = lane >> 4;          // 4 node-groups per wave
    const int l16  = lane & 15;          // 16 lanes x uint4(16B) = 256B row
    const int node = blockIdx.x * 16 + wave * 4 + grp;
    if (node >= n) return;

    const float* __restrict__ disb = dis + net * n;
    const int*   __restrict__ offb = off + net * n;
    const int*   __restrict__ degb = degc + net * n;

    const float ds  = disb[node];
    const float inv = ds * ds;                 // 1/(deg+1)
    const uint4* __restrict__ linv = (const uint4*)lin;   // row stride: 16 uint4

    float acc[8];
    {
        const uint4 su = linv[(size_t)node * 16 + l16];
        const float2 p0 = bfp2f(su.x), p1 = bfp2f(su.y), p2 = bfp2f(su.z), p3 = bfp2f(su.w);
        acc[0] = p0.x * inv; acc[1] = p0.y * inv;
        acc[2] = p1.x * inv; acc[3] = p1.y * inv;
        acc[4] = p2.x * inv; acc[5] = p2.y * inv;
        acc[6] = p3.x * inv; acc[7] = p3.y * inv;
    }

    const int start = offb[node];
    const int cnt   = degb[node];
    for (int j = 0; j < cnt; j += 4) {         // masked batches: no serial tail
        const int b0 = start + j;
        const int s0 = ebuf[b0];
        const int s1 = ebuf[j + 1 < cnt ? b0 + 1 : b0];
        const int s2 = ebuf[j + 2 < cnt ? b0 + 2 : b0];
        const int s3 = ebuf[j + 3 < cnt ? b0 + 3 : b0];
        const float n0 = disb[s0] * ds;
        const float n1 = j + 1 < cnt ? disb[s1] * ds : 0.0f;
        const float n2 = j + 2 < cnt ? disb[s2] * ds : 0.0f;
        const float n3 = j + 3 < cnt ? disb[s3] * ds : 0.0f;
        const uint4 u0 = linv[(size_t)s0 * 16 + l16];
        const uint4 u1 = linv[(size_t)s1 * 16 + l16];
        const uint4 u2 = linv[(size_t)s2 * 16 + l16];
        const uint4 u3 = linv[(size_t)s3 * 16 + l16];
        acc8(acc, u0, n0); acc8(acc, u1, n1); acc8(acc, u2, n2); acc8(acc, u3, n3);
    }

    const float4 bb0 = ((const float4*)bias)[l16 * 2];
    const float4 bb1 = ((const float4*)bias)[l16 * 2 + 1];
    acc[0] += bb0.x; acc[1] += bb0.y; acc[2] += bb0.z; acc[3] += bb0.w;
    acc[4] += bb1.x; acc[5] += bb1.y; acc[6] += bb1.z; acc[7] += bb1.w;
#pragma unroll
    for (int k = 0; k < 8; ++k) acc[k] = acc[k] > 0.0f ? acc[k] : 0.0f;

    uint4 pz;
    pz.x = (unsigned)f2bf(acc[0]) | ((unsigned)f2bf(acc[1]) << 16);
    pz.y = (unsigned)f2bf(acc[2]) | ((unsigned)f2bf(acc[3]) << 16);
    pz.z = (unsigned)f2bf(acc[4]) | ((unsigned)f2bf(acc[5]) << 16);
    pz.w = (unsigned)f2bf(acc[6]) | ((unsigned)f2bf(acc[7]) << 16);
    ((uint4*)outb)[(size_t)node * 16 + l16] = pz;
}

// ---------- gather conv (64-d): 8 lanes/node, uint4 rows, 8 nodes/wave ----------
__global__ __launch_bounds__(256) void gather_out_64_v2(
        const unsigned short* __restrict__ lin0, const unsigned short* __restrict__ lin1,
        const int* __restrict__ off, const int* __restrict__ degc,
        const int* __restrict__ ebuf, const float* __restrict__ dis,
        const float* __restrict__ bias,
        float* __restrict__ out0, float* __restrict__ out1,
        unsigned short* __restrict__ zb0, unsigned short* __restrict__ zb1, int n) {
    const int net = blockIdx.y;
    const unsigned short* __restrict__ lin = net ? lin1 : lin0;
    float* __restrict__ outp = net ? out1 : out0;
    unsigned short* __restrict__ zb = net ? zb1 : zb0;

    const int wave = threadIdx.x >> 6;
    const int lane = threadIdx.x & 63;
    const int grp  = lane >> 3;          // 8 node-groups per wave
    const int l8   = lane & 7;           // 8 lanes x uint4(16B) = 128B row
    const int node = blockIdx.x * 32 + wave * 8 + grp;
    if (node >= n) return;

    const float* __restrict__ disb = dis + net * n;
    const int*   __restrict__ offb = off + net * n;
    const int*   __restrict__ degb = degc + net * n;

    const float ds  = disb[node];
    const float inv = ds * ds;
    const uint4* __restrict__ linv = (const uint4*)lin;   // row stride: 8 uint4

    float acc[8];
    {
        const uint4 su = linv[(size_t)node * 8 + l8];
        const float2 p0 = bfp2f(su.x), p1 = bfp2f(su.y), p2 = bfp2f(su.z), p3 = bfp2f(su.w);
        acc[0] = p0.x * inv; acc[1] = p0.y * inv;
        acc[2] = p1.x * inv; acc[3] = p1.y * inv;
        acc[4] = p2.x * inv; acc[5] = p2.y * inv;
        acc[6] = p3.x * inv; acc[7] = p3.y * inv;
    }

    const int start = offb[node];
    const int cnt   = degb[node];
    for (int j = 0; j < cnt; j += 4) {
        const int b0 = start + j;
        const int s0 = ebuf[b0];
        const int s1 = ebuf[j + 1 < cnt ? b0 + 1 : b0];
        const int s2 = ebuf[j + 2 < cnt ? b0 + 2 : b0];
        const int s3 = ebuf[j + 3 < cnt ? b0 + 3 : b0];
        const float n0 = disb[s0] * ds;
        const float n1 = j + 1 < cnt ? disb[s1] * ds : 0.0f;
        const float n2 = j + 2 < cnt ? disb[s2] * ds : 0.0f;
        const float n3 = j + 3 < cnt ? disb[s3] * ds : 0.0f;
        const uint4 u0 = linv[(size_t)s0 * 8 + l8];
        const uint4 u1 = linv[(size_t)s1 * 8 + l8];
        const uint4 u2 = linv[(size_t)s2 * 8 + l8];
        const uint4 u3 = linv[(size_t)s3 * 8 + l8];
        acc8(acc, u0, n0); acc8(acc, u1, n1); acc8(acc, u2, n2); acc8(acc, u3, n3);
    }

    const float4 bb0 = ((const float4*)bias)[l8 * 2];
    const float4 bb1 = ((const float4*)bias)[l8 * 2 + 1];
    const float z0 = acc[0] + bb0.x, z1 = acc[1] + bb0.y, z2 = acc[2] + bb0.z, z3 = acc[3] + bb0.w;
    const float z4 = acc[4] + bb1.x, z5 = acc[5] + bb1.y, z6 = acc[6] + bb1.z, z7 = acc[7] + bb1.w;

    float4 w0; w0.x = z0; w0.y = z1; w0.z = z2; w0.w = z3;
    float4 w1; w1.x = z4; w1.y = z5; w1.z = z6; w1.w = z7;
    ((float4*)outp)[(size_t)node * 16 + l8 * 2]     = w0;
    ((float4*)outp)[(size_t)node * 16 + l8 * 2 + 1] = w1;

    uint4 pz;
    pz.x = (unsigned)f2bf(z0) | ((unsigned)f2bf(z1) << 16);
    pz.y = (unsigned)f2bf(z2) | ((unsigned)f2bf(z3) << 16);
    pz.z = (unsigned)f2bf(z4) | ((unsigned)f2bf(z5) << 16);
    pz.w = (unsigned)f2bf(z6) | ((unsigned)f2bf(z7) << 16);
    ((uint4*)zb)[(size_t)node * 8 + l8] = pz;
}

// ---------- decoder (bf16 z): p[e] = sigmoid(dot(Z[src], Z[dst])), both nets ----------
__global__ __launch_bounds__(256) void decoder2(
        const unsigned short* __restrict__ Zb0, const unsigned short* __restrict__ Zb1,
        const int* __restrict__ s_ei, const int* __restrict__ t_ei,
        float* __restrict__ out0, float* __restrict__ out1) {
    const int net = blockIdx.y;
    const unsigned short* __restrict__ Zb = net ? Zb1 : Zb0;
    const int* __restrict__ ei = net ? t_ei : s_ei;
    float* __restrict__ op = net ? out1 : out0;

    const int tid  = blockIdx.x * blockDim.x + threadIdx.x;
    const int edge = tid >> 3;   // 8 lanes per edge
    const int lane = tid & 7;
    if (edge >= N_EDGES) return;
    const int s = ei[edge], d = ei[N_EDGES + edge];
    const uint4 ua = *(const uint4*)&Zb[(size_t)s * OUT_D + lane * 8];
    const uint4 ub = *(const uint4*)&Zb[(size_t)d * OUT_D + lane * 8];
    float p = 0.0f;
    {
        const float2 a0 = bfp2f(ua.x), b0 = bfp2f(ub.x);
        const float2 a1 = bfp2f(ua.y), b1 = bfp2f(ub.y);
        const float2 a2 = bfp2f(ua.z), b2 = bfp2f(ub.z);
        const float2 a3 = bfp2f(ua.w), b3 = bfp2f(ub.w);
        p = fmaf(a0.x, b0.x, p); p = fmaf(a0.y, b0.y, p);
        p = fmaf(a1.x, b1.x, p); p = fmaf(a1.y, b1.y, p);
        p = fmaf(a2.x, b2.x, p); p = fmaf(a2.y, b2.y, p);
        p = fmaf(a3.x, b3.x, p); p = fmaf(a3.y, b3.y, p);
    }
    p += __shfl_down(p, 4, 8);
    p += __shfl_down(p, 2, 8);
    p += __shfl_down(p, 1, 8);
    if (lane == 0) op[edge] = 1.0f / (1.0f + expf(-p));
}

extern "C" void kernel_launch(void* const* d_in, const int* in_sizes, int n_in,
                              void* d_out, int out_size, void* d_ws, size_t ws_size,
                              hipStream_t stream) {
    const float* xs  = (const float*)d_in[0];
    const float* xt  = (const float*)d_in[1];
    const int* s_ei  = (const int*)d_in[2];
    const int* t_ei  = (const int*)d_in[3];
    const float* W1  = (const float*)d_in[4];
    const float* b1  = (const float*)d_in[5];
    const float* W2  = (const float*)d_in[6];
    const float* b2  = (const float*)d_in[7];
    const float* W3  = (const float*)d_in[8];
    const float* b3  = (const float*)d_in[9];

    // workspace layout (~110 MB): 4 big bf16 feature buffers + CSR (concat 2N/2E)
    unsigned short* Lb1 = (unsigned short*)d_ws;                 // NPAD*128 bf16 (lin conv1, net s)
    unsigned short* Lb2 = Lb1 + (size_t)N_PAD * HID;             // NPAD*128 bf16 (lin conv1, net t)
    unsigned short* Hb1 = Lb2 + (size_t)N_PAD * HID;             // NPAD*128 bf16 (h, net s)
    unsigned short* Hb2 = Hb1 + (size_t)N_PAD * HID;             // NPAD*128 bf16 (h, net t)
    // aliases (lifetime-disjoint):
    //   conv3 lin overlays conv1 lin; z overlays h
    //   binned edge records overlay Hb (dead before gather_relu writes Hb)
    unsigned short* L2b1 = Lb1;                                  // NPAD*64 bf16 (lin conv3, s)
    unsigned short* L2b2 = Lb2;
    unsigned short* Zb1  = Hb1;                                  // NPAD*64 bf16 (z copy, s)
    unsigned short* Zb2  = Hb2;
    uint2* binned       = (uint2*)Hb1;                           // NBUCK*BCAP*8B = 19.3 MB
    unsigned short* Wp1 = Hb2 + (size_t)N_PAD * HID;             // 128*128 bf16
    unsigned short* Wp2 = Wp1 + 128 * HID;                       // 128*128 bf16
    unsigned short* W3p = Wp2 + 128 * HID;                       // 128*64 bf16
    float* dis          = (float*)(W3p + 128 * OUT_D);           // 2N f
    int*   deg          = (int*)(dis + TOTN);                    // 2N i
    int*   off          = deg + TOTN;                            // 2N i
    int*   ebuf         = off + TOTN;                            // 2E i
    int*   tail         = ebuf + 2 * N_EDGES;                    // NBUCK i
    int*   bbase        = tail + NBUCK;                          // NBUCK i

    float* out = (float*)d_out;
    float* out_zs = out;                                 // N*64
    float* out_zt = out + (size_t)N_NODES * OUT_D;       // N*64
    float* out_ps = out + 2 * (size_t)N_NODES * OUT_D;   // E
    float* out_pt = out_ps + N_EDGES;                    // E

    // ---- CSR build via bucket binning ----
    hipMemsetAsync(tail, 0, NBUCK * sizeof(int), stream);
    bin_edges<<<BIN_NBLK, 256, 0, stream>>>(s_ei, t_ei, tail, binned);
    scan_tail<<<1, 256, 0, stream>>>(tail, bbase);
    build_csr<<<NBUCK, 256, 0, stream>>>(tail, bbase, binned, off, deg, dis, ebuf);

    // ---- weights (one tiny launch) ----
    pack_all<<<(2 * 128 * HID + 128 * OUT_D + 255) / 256, 256, 0, stream>>>(
        W1, W2, W3, Wp1, Wp2, W3p);

    // ---- conv1/conv2 lin: fused fp32->bf16 convert + MFMA GEMM, both nets ----
    mfma_gemm_f32<HID><<<dim3(ROW_BLKS, 2), 256, 0, stream>>>(
        xs, xt, Wp1, Wp2, Lb1, Lb2, N_NODES);

    // ---- gather + bias + relu, both nets ----
    gather_relu_128_v2<<<dim3((N_NODES + 15) / 16, 2), 256, 0, stream>>>(
        Lb1, Lb2, off, deg, ebuf, dis, b1, b2, Hb1, Hb2, N_NODES);

    // ---- conv3 lin: MFMA GEMM (bf16 in), both nets ----
    mfma_gemm_bf<OUT_D><<<dim3(ROW_BLKS, 2), 256, 0, stream>>>(
        Hb1, Hb2, W3p, L2b1, L2b2, N_NODES);

    // ---- gather -> z (fp32 out) + bf16 copy, both nets ----
    gather_out_64_v2<<<dim3((N_NODES + 31) / 32, 2), 256, 0, stream>>>(
        L2b1, L2b2, off, deg, ebuf, dis, b3, out_zs, out_zt, Zb1, Zb2, N_NODES);

    // ---- decoder, both nets ----
    decoder2<<<dim3((int)(((size_t)N_EDGES * 8 + 255) / 256), 2), 256, 0, stream>>>(
        Zb1, Zb2, s_ei, t_ei, out_ps, out_pt);
}

// Round 4
// 324.033 us; speedup vs baseline: 1.6516x; 1.0443x over previous
//
#include <hip/hip_runtime.h>

// Problem constants (match reference)
constexpr int N_NODES = 100000;
constexpr int N_EDGES = 500000;
constexpr int HID     = 128;   // conv1/conv2 output dim
constexpr int OUT_D   = 64;    // conv3 output dim
constexpr int TOTN    = 2 * N_NODES;   // both networks concatenated

constexpr int ROW_BLKS = (N_NODES + 63) / 64;   // 1563 blocks of 64 rows
constexpr int N_PAD    = ROW_BLKS * 64;          // 100032 padded rows

// ---- CSR build via coarse bucket binning ----
constexpr int BK_LG    = 10;                      // 1024 nodes per bucket
constexpr int BK_W     = 1 << BK_LG;
constexpr int NBUCK    = (TOTN + BK_W - 1) >> BK_LG;   // 196
constexpr int BCAP     = 6144;                    // mean 5120, sigma~72 -> +14 sigma
constexpr int BCAP_PAD = BCAP + 3 * BK_W;         // 9216: room for per-node 4-align padding
constexpr int BIN_TILE = 4096;                    // edges per bin block
constexpr int BIN_NBLK = (2 * N_EDGES + BIN_TILE - 1) / BIN_TILE;  // 245
constexpr int PACK_N   = 2 * 128 * HID + 128 * OUT_D;              // 40960 weight elems
constexpr int PACK_BLK = (PACK_N + 255) / 256;                     // 160
static_assert(NBUCK <= 256, "bucket scan must fit one block");

typedef __attribute__((ext_vector_type(8))) short short8;
typedef __attribute__((ext_vector_type(4))) float float4v;

// float -> bf16 (round-to-nearest-even), as raw ushort
__device__ __forceinline__ unsigned short f2bf(float f) {
    unsigned u = __float_as_uint(f);
    u += 0x7fffu + ((u >> 16) & 1u);
    return (unsigned short)(u >> 16);
}
// packed pair of bf16 (lo = even col, hi = odd col) -> two floats
__device__ __forceinline__ float2 bfp2f(unsigned u) {
    float2 r;
    r.x = __uint_as_float(u << 16);
    r.y = __uint_as_float(u & 0xffff0000u);
    return r;
}

// 8 bf16 (one uint4) scaled-accumulate into acc[0..7] (static indices only)
__device__ __forceinline__ void acc8(float* acc, uint4 u, float nm) {
    const float2 p0 = bfp2f(u.x), p1 = bfp2f(u.y), p2 = bfp2f(u.z), p3 = bfp2f(u.w);
    acc[0] = fmaf(p0.x, nm, acc[0]); acc[1] = fmaf(p0.y, nm, acc[1]);
    acc[2] = fmaf(p1.x, nm, acc[2]); acc[3] = fmaf(p1.y, nm, acc[3]);
    acc[4] = fmaf(p2.x, nm, acc[4]); acc[5] = fmaf(p2.y, nm, acc[5]);
    acc[6] = fmaf(p3.x, nm, acc[6]); acc[7] = fmaf(p3.y, nm, acc[7]);
}

// ---------- weight packing helper (MFMA B-fragment order, bf16) ----------
__device__ __forceinline__ void pack_one(const float* __restrict__ W,
                                         unsigned short* __restrict__ Wp,
                                         int t, int COLS, int lg) {
    const int k = t >> lg, nn = t & (COLS - 1);
    const int kb = k >> 5, rem = k & 31, quad = rem >> 3, j = rem & 7;
    Wp[((size_t)(kb * 4 + quad) * COLS + nn) * 8 + j] = f2bf(W[t]);
}

// ---------- P1: bin edges into coarse buckets (+ fused weight packing) ----------
__global__ __launch_bounds__(256) void bin_edges(const int* __restrict__ s_ei,
                                                 const int* __restrict__ t_ei,
                                                 int* __restrict__ tail,
                                                 uint2* __restrict__ binned,
                                                 const float* __restrict__ W1,
                                                 const float* __restrict__ W2,
                                                 const float* __restrict__ W3,
                                                 unsigned short* __restrict__ Wp1,
                                                 unsigned short* __restrict__ Wp2,
                                                 unsigned short* __restrict__ W3p) {
    if (blockIdx.x >= BIN_NBLK) {   // fused weight-packing blocks
        const int idx = (blockIdx.x - BIN_NBLK) * 256 + threadIdx.x;
        if (idx < 128 * HID) {
            pack_one(W1, Wp1, idx, HID, 7);
        } else if (idx < 2 * 128 * HID) {
            pack_one(W2, Wp2, idx - 128 * HID, HID, 7);
        } else if (idx < PACK_N) {
            pack_one(W3, W3p, idx - 2 * 128 * HID, OUT_D, 6);
        }
        return;
    }

    __shared__ int hist[NBUCK];
    __shared__ int lcur[NBUCK];
    for (int i = threadIdx.x; i < NBUCK; i += 256) hist[i] = 0;
    __syncthreads();

    const int base_e = blockIdx.x * BIN_TILE;
    int esrc[16], egd[16], ebk[16];
#pragma unroll
    for (int k = 0; k < 16; ++k) {
        const int e = base_e + k * 256 + threadIdx.x;
        int s = 0, g = -1;
        if (e < N_EDGES) {
            s = s_ei[e];
            g = s_ei[N_EDGES + e];
        } else if (e < 2 * N_EDGES) {
            const int j = e - N_EDGES;
            s = t_ei[j];
            g = N_NODES + t_ei[N_EDGES + j];
        }
        esrc[k] = s; egd[k] = g;
        if (g >= 0) { ebk[k] = g >> BK_LG; atomicAdd(&hist[ebk[k]], 1); }
        else ebk[k] = -1;
    }
    __syncthreads();
    // reserve one contiguous range per (block, bucket)
    for (int i = threadIdx.x; i < NBUCK; i += 256) {
        const int h = hist[i];
        lcur[i] = h ? atomicAdd(&tail[i], h) : 0;
    }
    __syncthreads();
#pragma unroll
    for (int k = 0; k < 16; ++k) {
        if (ebk[k] >= 0) {
            const int p = atomicAdd(&lcur[ebk[k]], 1);     // LDS atomic -> global pos
            if (p < BCAP)
                binned[(size_t)ebk[k] * BCAP + p] = make_uint2((unsigned)esrc[k], (unsigned)egd[k]);
        }
    }
}

// ---------- P2: per-bucket CSR build (fixed-stride, 4-aligned node segments) ----------
__global__ __launch_bounds__(256) void build_csr(const int* __restrict__ tail,
                                                 const uint2* __restrict__ binned,
                                                 uint4* __restrict__ node_info,
                                                 float* __restrict__ dis,
                                                 int* __restrict__ ebuf) {
    __shared__ int hist[BK_W];
    __shared__ int ssum[256];
    const int b   = blockIdx.x;
    const int t   = threadIdx.x;
    const int gn0 = b << BK_LG;
    const int nn  = min(BK_W, TOTN - gn0);
    const int cnt = min(tail[b], BCAP);
    const int cbase = b * BCAP_PAD;
    const uint2* __restrict__ mine = binned + (size_t)b * BCAP;

    for (int i = t; i < BK_W; i += 256) hist[i] = 0;
    __syncthreads();
    for (int r = t; r < cnt; r += 256)
        atomicAdd(&hist[(int)mine[r].y - gn0], 1);
    __syncthreads();

    // exclusive scan over 1024 PADDED histogram entries (4 per thread, pad to x4)
    const int h0 = hist[t * 4 + 0], h1 = hist[t * 4 + 1];
    const int h2 = hist[t * 4 + 2], h3 = hist[t * 4 + 3];
    const int p0 = (h0 + 3) & ~3, p1 = (h1 + 3) & ~3;
    const int p2 = (h2 + 3) & ~3, p3 = (h3 + 3) & ~3;
    const int ts = p0 + p1 + p2 + p3;
    ssum[t] = ts;
    __syncthreads();
    for (int o = 1; o < 256; o <<= 1) {
        const int x = (t >= o) ? ssum[t - o] : 0;
        __syncthreads();
        if (t >= o) ssum[t] += x;
        __syncthreads();
    }
    const int ex = ssum[t] - ts;
    const int o0 = ex, o1 = ex + p0, o2 = o1 + p1, o3 = o2 + p2;

    // node outputs (coalesced): node_info = {off, deg, bits(dis), 0}
    if (t * 4 + 0 < nn) { const int g = gn0 + t * 4 + 0; const float d = rsqrtf((float)h0 + 1.0f);
        node_info[g] = make_uint4((unsigned)(cbase + o0), (unsigned)h0, __float_as_uint(d), 0u); dis[g] = d; }
    if (t * 4 + 1 < nn) { const int g = gn0 + t * 4 + 1; const float d = rsqrtf((float)h1 + 1.0f);
        node_info[g] = make_uint4((unsigned)(cbase + o1), (unsigned)h1, __float_as_uint(d), 0u); dis[g] = d; }
    if (t * 4 + 2 < nn) { const int g = gn0 + t * 4 + 2; const float d = rsqrtf((float)h2 + 1.0f);
        node_info[g] = make_uint4((unsigned)(cbase + o2), (unsigned)h2, __float_as_uint(d), 0u); dis[g] = d; }
    if (t * 4 + 3 < nn) { const int g = gn0 + t * 4 + 3; const float d = rsqrtf((float)h3 + 1.0f);
        node_info[g] = make_uint4((unsigned)(cbase + o3), (unsigned)h3, __float_as_uint(d), 0u); dis[g] = d; }
    __syncthreads();

    // repurpose hist as running cursors (padded exclusive offsets)
    hist[t * 4 + 0] = o0; hist[t * 4 + 1] = o1; hist[t * 4 + 2] = o2; hist[t * 4 + 3] = o3;
    __syncthreads();

    // scatter into block-local CSR window (single XCD L2)
    for (int r = t; r < cnt; r += 256) {
        const uint2 rec = mine[r];
        const int p = atomicAdd(&hist[(int)rec.y - gn0], 1);
        ebuf[cbase + p] = (int)rec.x;
    }
}

// ---------- MFMA GEMM, fp32 A with fused bf16 convert; B staged in LDS ----------
template <int COLS>
__global__ __launch_bounds__(256) void mfma_gemm_f32(const float* __restrict__ X0,
                                                     const float* __restrict__ X1,
                                                     const unsigned short* __restrict__ Wp0,
                                                     const unsigned short* __restrict__ Wp1,
                                                     unsigned short* __restrict__ Y0,
                                                     unsigned short* __restrict__ Y1, int n) {
    __shared__ unsigned short Bs[16 * COLS * 8];   // full packed W: 32 KB (128) / 16 KB (64)

    const float* __restrict__ X = blockIdx.y ? X1 : X0;
    const unsigned short* __restrict__ Wp = blockIdx.y ? Wp1 : Wp0;
    unsigned short* __restrict__ Y = blockIdx.y ? Y1 : Y0;

    const int wave = threadIdx.x >> 6;
    const int lane = threadIdx.x & 63;
    const int quad = lane >> 4;
    const int l16  = lane & 15;
    const int rowbase = blockIdx.x * 64 + wave * 16;
    const int row = rowbase + l16;
    const int rc  = row < n ? row : n - 1;    // clamp: garbage rows never stored

    // issue ALL 8 A-tile loads first (distinct regs -> 8 loads in flight)
    float4 f[8];
    const size_t arow = (size_t)rc * 128;
#pragma unroll
    for (int i = 0; i < 8; ++i)
        f[i] = *(const float4*)&X[arow + (i >> 1) * 32 + quad * 8 + (i & 1) * 4];

    // stage packed W into LDS (overlaps with A loads in flight)
    {
        const uint4* __restrict__ wsrc = (const uint4*)Wp;
        uint4* __restrict__ wdst = (uint4*)Bs;
        constexpr int CH = 16 * COLS;              // 16B chunks
#pragma unroll
        for (int i = 0; i < CH / 256; ++i)
            wdst[i * 256 + threadIdx.x] = wsrc[i * 256 + threadIdx.x];
    }
    __syncthreads();

    // convert A to bf16 fragments
    short8 a[4];
#pragma unroll
    for (int kb = 0; kb < 4; ++kb) {
        const float4 g0 = f[2 * kb], g1 = f[2 * kb + 1];
        short8 v;
        v[0] = (short)f2bf(g0.x); v[1] = (short)f2bf(g0.y);
        v[2] = (short)f2bf(g0.z); v[3] = (short)f2bf(g0.w);
        v[4] = (short)f2bf(g1.x); v[5] = (short)f2bf(g1.y);
        v[6] = (short)f2bf(g1.z); v[7] = (short)f2bf(g1.w);
        a[kb] = v;
    }

#pragma unroll
    for (int ct = 0; ct < COLS / 16; ++ct) {
        const int col = ct * 16 + l16;
        float4v acc = {0.0f, 0.0f, 0.0f, 0.0f};
#pragma unroll
        for (int kb = 0; kb < 4; ++kb) {
            const short8 b = *(const short8*)&Bs[((kb * 4 + quad) * COLS + col) * 8];
            acc = __builtin_amdgcn_mfma_f32_16x16x32_bf16(a[kb], b, acc, 0, 0, 0);
        }
#pragma unroll
        for (int r = 0; r < 4; ++r) {
            const int orow = rowbase + quad * 4 + r;   // C/D: row=(lane>>4)*4+reg, col=lane&15
            if (orow < n) Y[(size_t)orow * COLS + col] = f2bf(acc[r]);
        }
    }
}

// ---------- MFMA GEMM, bf16 input (conv3); B staged in LDS ----------
template <int COLS>
__global__ __launch_bounds__(256) void mfma_gemm_bf(const unsigned short* __restrict__ Xb0,
                                                    const unsigned short* __restrict__ Xb1,
                                                    const unsigned short* __restrict__ Wp,
                                                    unsigned short* __restrict__ Y0,
                                                    unsigned short* __restrict__ Y1, int n) {
    __shared__ unsigned short Bs[16 * COLS * 8];

    const unsigned short* __restrict__ Xb = blockIdx.y ? Xb1 : Xb0;
    unsigned short* __restrict__ Y = blockIdx.y ? Y1 : Y0;

    const int wave = threadIdx.x >> 6;
    const int lane = threadIdx.x & 63;
    const int quad = lane >> 4;
    const int l16  = lane & 15;
    const int rowbase = blockIdx.x * 64 + wave * 16;

    // issue all 4 A loads first
    short8 a[4];
    const size_t arow = (size_t)(rowbase + l16) * 128;
#pragma unroll
    for (int kb = 0; kb < 4; ++kb)
        a[kb] = *(const short8*)&Xb[arow + kb * 32 + quad * 8];

    // stage packed W into LDS
    {
        const uint4* __restrict__ wsrc = (const uint4*)Wp;
        uint4* __restrict__ wdst = (uint4*)Bs;
        constexpr int CH = 16 * COLS;
#pragma unroll
        for (int i = 0; i < CH / 256; ++i)
            wdst[i * 256 + threadIdx.x] = wsrc[i * 256 + threadIdx.x];
    }
    __syncthreads();

#pragma unroll
    for (int ct = 0; ct < COLS / 16; ++ct) {
        const int col = ct * 16 + l16;
        float4v acc = {0.0f, 0.0f, 0.0f, 0.0f};
#pragma unroll
        for (int kb = 0; kb < 4; ++kb) {
            const short8 b = *(const short8*)&Bs[((kb * 4 + quad) * COLS + col) * 8];
            acc = __builtin_amdgcn_mfma_f32_16x16x32_bf16(a[kb], b, acc, 0, 0, 0);
        }
#pragma unroll
        for (int r = 0; r < 4; ++r) {
            const int row = rowbase + quad * 4 + r;
            if (row < n) Y[(size_t)row * COLS + col] = f2bf(acc[r]);
        }
    }
}

// ---------- gather conv (128-d): 16 lanes/node, uint4 rows, 8-deep batches ----------
__global__ __launch_bounds__(256) void gather_relu_128_v3(
        const unsigned short* __restrict__ lin0, const unsigned short* __restrict__ lin1,
        const uint4* __restrict__ node_info, const int* __restrict__ ebuf,
        const float* __restrict__ dis,
        const float* __restrict__ bias0, const float* __restrict__ bias1,
        unsigned short* __restrict__ out0, unsigned short* __restrict__ out1, int n) {
    const int net = blockIdx.y;
    const unsigned short* __restrict__ lin = net ? lin1 : lin0;
    unsigned short* __restrict__ outb = net ? out1 : out0;
    const float* __restrict__ bias = net ? bias1 : bias0;

    const int wave = threadIdx.x >> 6;
    const int lane = threadIdx.x & 63;
    const int grp  = lane >> 4;          // 4 node-groups per wave
    const int l16  = lane & 15;          // 16 lanes x uint4(16B) = 256B row
    const int node = blockIdx.x * 16 + wave * 4 + grp;
    if (node >= n) return;

    const float* __restrict__ disb = dis + net * n;
    const uint4 ni = node_info[(size_t)net * n + node];
    const int   start = (int)ni.x;
    const int   cnt   = (int)ni.y;
    const float ds    = __uint_as_float(ni.z);
    const float inv   = ds * ds;               // 1/(deg+1)
    const uint4* __restrict__ linv = (const uint4*)lin;   // row stride: 16 uint4

    float acc[8];
    {
        const uint4 su = linv[(size_t)node * 16 + l16];
        const float2 p0 = bfp2f(su.x), p1 = bfp2f(su.y), p2 = bfp2f(su.z), p3 = bfp2f(su.w);
        acc[0] = p0.x * inv; acc[1] = p0.y * inv;
        acc[2] = p1.x * inv; acc[3] = p1.y * inv;
        acc[4] = p2.x * inv; acc[5] = p2.y * inv;
        acc[6] = p3.x * inv; acc[7] = p3.y * inv;
    }

    for (int j = 0; j < cnt; j += 8) {         // 8-deep masked batches
        const int b0 = start + j;              // 4-aligned by construction
        const int4 qa = *(const int4*)&ebuf[b0];
        const int4 qb = *(const int4*)&ebuf[b0 + 4];
        const int s0 = qa.x;
        const int s1 = j + 1 < cnt ? qa.y : qa.x;
        const int s2 = j + 2 < cnt ? qa.z : qa.x;
        const int s3 = j + 3 < cnt ? qa.w : qa.x;
        const int s4 = j + 4 < cnt ? qb.x : qa.x;
        const int s5 = j + 5 < cnt ? qb.y : qa.x;
        const int s6 = j + 6 < cnt ? qb.z : qa.x;
        const int s7 = j + 7 < cnt ? qb.w : qa.x;
        const float d0 = disb[s0], d1 = disb[s1], d2 = disb[s2], d3 = disb[s3];
        const float d4 = disb[s4], d5 = disb[s5], d6 = disb[s6], d7 = disb[s7];
        const uint4 u0 = linv[(size_t)s0 * 16 + l16];
        const uint4 u1 = linv[(size_t)s1 * 16 + l16];
        const uint4 u2 = linv[(size_t)s2 * 16 + l16];
        const uint4 u3 = linv[(size_t)s3 * 16 + l16];
        const uint4 u4 = linv[(size_t)s4 * 16 + l16];
        const uint4 u5 = linv[(size_t)s5 * 16 + l16];
        const uint4 u6 = linv[(size_t)s6 * 16 + l16];
        const uint4 u7 = linv[(size_t)s7 * 16 + l16];
        const float n0 = d0 * ds;
        const float n1 = j + 1 < cnt ? d1 * ds : 0.0f;
        const float n2 = j + 2 < cnt ? d2 * ds : 0.0f;
        const float n3 = j + 3 < cnt ? d3 * ds : 0.0f;
        const float n4 = j + 4 < cnt ? d4 * ds : 0.0f;
        const float n5 = j + 5 < cnt ? d5 * ds : 0.0f;
        const float n6 = j + 6 < cnt ? d6 * ds : 0.0f;
        const float n7 = j + 7 < cnt ? d7 * ds : 0.0f;
        acc8(acc, u0, n0); acc8(acc, u1, n1); acc8(acc, u2, n2); acc8(acc, u3, n3);
        acc8(acc, u4, n4); acc8(acc, u5, n5); acc8(acc, u6, n6); acc8(acc, u7, n7);
    }

    const float4 bb0 = ((const float4*)bias)[l16 * 2];
    const float4 bb1 = ((const float4*)bias)[l16 * 2 + 1];
    acc[0] += bb0.x; acc[1] += bb0.y; acc[2] += bb0.z; acc[3] += bb0.w;
    acc[4] += bb1.x; acc[5] += bb1.y; acc[6] += bb1.z; acc[7] += bb1.w;
#pragma unroll
    for (int k = 0; k < 8; ++k) acc[k] = acc[k] > 0.0f ? acc[k] : 0.0f;

    uint4 pz;
    pz.x = (unsigned)f2bf(acc[0]) | ((unsigned)f2bf(acc[1]) << 16);
    pz.y = (unsigned)f2bf(acc[2]) | ((unsigned)f2bf(acc[3]) << 16);
    pz.z = (unsigned)f2bf(acc[4]) | ((unsigned)f2bf(acc[5]) << 16);
    pz.w = (unsigned)f2bf(acc[6]) | ((unsigned)f2bf(acc[7]) << 16);
    ((uint4*)outb)[(size_t)node * 16 + l16] = pz;
}

// ---------- gather conv (64-d): 8 lanes/node, uint4 rows, 8-deep batches ----------
__global__ __launch_bounds__(256) void gather_out_64_v3(
        const unsigned short* __restrict__ lin0, const unsigned short* __restrict__ lin1,
        const uint4* __restrict__ node_info, const int* __restrict__ ebuf,
        const float* __restrict__ dis, const float* __restrict__ bias,
        float* __restrict__ out0, float* __restrict__ out1,
        unsigned short* __restrict__ zb0, unsigned short* __restrict__ zb1, int n) {
    const int net = blockIdx.y;
    const unsigned short* __restrict__ lin = net ? lin1 : lin0;
    float* __restrict__ outp = net ? out1 : out0;
    unsigned short* __restrict__ zb = net ? zb1 : zb0;

    const int wave = threadIdx.x >> 6;
    const int lane = threadIdx.x & 63;
    const int grp  = lane >> 3;          // 8 node-groups per wave
    const int l8   = lane & 7;           // 8 lanes x uint4(16B) = 128B row
    const int node = blockIdx.x * 32 + wave * 8 + grp;
    if (node >= n) return;

    const float* __restrict__ disb = dis + net * n;
    const uint4 ni = node_info[(size_t)net * n + node];
    const int   start = (int)ni.x;
    const int   cnt   = (int)ni.y;
    const float ds    = __uint_as_float(ni.z);
    const float inv   = ds * ds;
    const uint4* __restrict__ linv = (const uint4*)lin;   // row stride: 8 uint4

    float acc[8];
    {
        const uint4 su = linv[(size_t)node * 8 + l8];
        const float2 p0 = bfp2f(su.x), p1 = bfp2f(su.y), p2 = bfp2f(su.z), p3 = bfp2f(su.w);
        acc[0] = p0.x * inv; acc[1] = p0.y * inv;
        acc[2] = p1.x * inv; acc[3] = p1.y * inv;
        acc[4] = p2.x * inv; acc[5] = p2.y * inv;
        acc[6] = p3.x * inv; acc[7] = p3.y * inv;
    }

    for (int j = 0; j < cnt; j += 8) {
        const int b0 = start + j;
        const int4 qa = *(const int4*)&ebuf[b0];
        const int4 qb = *(const int4*)&ebuf[b0 + 4];
        const int s0 = qa.x;
        const int s1 = j + 1 < cnt ? qa.y : qa.x;
        const int s2 = j + 2 < cnt ? qa.z : qa.x;
        const int s3 = j + 3 < cnt ? qa.w : qa.x;
        const int s4 = j + 4 < cnt ? qb.x : qa.x;
        const int s5 = j + 5 < cnt ? qb.y : qa.x;
        const int s6 = j + 6 < cnt ? qb.z : qa.x;
        const int s7 = j + 7 < cnt ? qb.w : qa.x;
        const float d0 = disb[s0], d1 = disb[s1], d2 = disb[s2], d3 = disb[s3];
        const float d4 = disb[s4], d5 = disb[s5], d6 = disb[s6], d7 = disb[s7];
        const uint4 u0 = linv[(size_t)s0 * 8 + l8];
        const uint4 u1 = linv[(size_t)s1 * 8 + l8];
        const uint4 u2 = linv[(size_t)s2 * 8 + l8];
        const uint4 u3 = linv[(size_t)s3 * 8 + l8];
        const uint4 u4 = linv[(size_t)s4 * 8 + l8];
        const uint4 u5 = linv[(size_t)s5 * 8 + l8];
        const uint4 u6 = linv[(size_t)s6 * 8 + l8];
        const uint4 u7 = linv[(size_t)s7 * 8 + l8];
        const float n0 = d0 * ds;
        const float n1 = j + 1 < cnt ? d1 * ds : 0.0f;
        const float n2 = j + 2 < cnt ? d2 * ds : 0.0f;
        const float n3 = j + 3 < cnt ? d3 * ds : 0.0f;
        const float n4 = j + 4 < cnt ? d4 * ds : 0.0f;
        const float n5 = j + 5 < cnt ? d5 * ds : 0.0f;
        const float n6 = j + 6 < cnt ? d6 * ds : 0.0f;
        const float n7 = j + 7 < cnt ? d7 * ds : 0.0f;
        acc8(acc, u0, n0); acc8(acc, u1, n1); acc8(acc, u2, n2); acc8(acc, u3, n3);
        acc8(acc, u4, n4); acc8(acc, u5, n5); acc8(acc, u6, n6); acc8(acc, u7, n7);
    }

    const float4 bb0 = ((const float4*)bias)[l8 * 2];
    const float4 bb1 = ((const float4*)bias)[l8 * 2 + 1];
    const float z0 = acc[0] + bb0.x, z1 = acc[1] + bb0.y, z2 = acc[2] + bb0.z, z3 = acc[3] + bb0.w;
    const float z4 = acc[4] + bb1.x, z5 = acc[5] + bb1.y, z6 = acc[6] + bb1.z, z7 = acc[7] + bb1.w;

    float4 w0; w0.x = z0; w0.y = z1; w0.z = z2; w0.w = z3;
    float4 w1; w1.x = z4; w1.y = z5; w1.z = z6; w1.w = z7;
    ((float4*)outp)[(size_t)node * 16 + l8 * 2]     = w0;
    ((float4*)outp)[(size_t)node * 16 + l8 * 2 + 1] = w1;

    uint4 pz;
    pz.x = (unsigned)f2bf(z0) | ((unsigned)f2bf(z1) << 16);
    pz.y = (unsigned)f2bf(z2) | ((unsigned)f2bf(z3) << 16);
    pz.z = (unsigned)f2bf(z4) | ((unsigned)f2bf(z5) << 16);
    pz.w = (unsigned)f2bf(z6) | ((unsigned)f2bf(z7) << 16);
    ((uint4*)zb)[(size_t)node * 8 + l8] = pz;
}

// ---------- decoder (bf16 z): p[e] = sigmoid(dot(Z[src], Z[dst])), both nets ----------
__global__ __launch_bounds__(256) void decoder2(
        const unsigned short* __restrict__ Zb0, const unsigned short* __restrict__ Zb1,
        const int* __restrict__ s_ei, const int* __restrict__ t_ei,
        float* __restrict__ out0, float* __restrict__ out1) {
    const int net = blockIdx.y;
    const unsigned short* __restrict__ Zb = net ? Zb1 : Zb0;
    const int* __restrict__ ei = net ? t_ei : s_ei;
    float* __restrict__ op = net ? out1 : out0;

    const int tid  = blockIdx.x * blockDim.x + threadIdx.x;
    const int edge = tid >> 3;   // 8 lanes per edge
    const int lane = tid & 7;
    if (edge >= N_EDGES) return;
    const int s = ei[edge], d = ei[N_EDGES + edge];
    const uint4 ua = *(const uint4*)&Zb[(size_t)s * OUT_D + lane * 8];
    const uint4 ub = *(const uint4*)&Zb[(size_t)d * OUT_D + lane * 8];
    float p = 0.0f;
    {
        const float2 a0 = bfp2f(ua.x), b0 = bfp2f(ub.x);
        const float2 a1 = bfp2f(ua.y), b1 = bfp2f(ub.y);
        const float2 a2 = bfp2f(ua.z), b2 = bfp2f(ub.z);
        const float2 a3 = bfp2f(ua.w), b3 = bfp2f(ub.w);
        p = fmaf(a0.x, b0.x, p); p = fmaf(a0.y, b0.y, p);
        p = fmaf(a1.x, b1.x, p); p = fmaf(a1.y, b1.y, p);
        p = fmaf(a2.x, b2.x, p); p = fmaf(a2.y, b2.y, p);
        p = fmaf(a3.x, b3.x, p); p = fmaf(a3.y, b3.y, p);
    }
    p += __shfl_down(p, 4, 8);
    p += __shfl_down(p, 2, 8);
    p += __shfl_down(p, 1, 8);
    if (lane == 0) op[edge] = 1.0f / (1.0f + expf(-p));
}

extern "C" void kernel_launch(void* const* d_in, const int* in_sizes, int n_in,
                              void* d_out, int out_size, void* d_ws, size_t ws_size,
                              hipStream_t stream) {
    const float* xs  = (const float*)d_in[0];
    const float* xt  = (const float*)d_in[1];
    const int* s_ei  = (const int*)d_in[2];
    const int* t_ei  = (const int*)d_in[3];
    const float* W1  = (const float*)d_in[4];
    const float* b1  = (const float*)d_in[5];
    const float* W2  = (const float*)d_in[6];
    const float* b2  = (const float*)d_in[7];
    const float* W3  = (const float*)d_in[8];
    const float* b3  = (const float*)d_in[9];

    // workspace layout (~115 MB)
    unsigned short* Lb1 = (unsigned short*)d_ws;                 // NPAD*128 bf16 (lin conv1, net s)
    unsigned short* Lb2 = Lb1 + (size_t)N_PAD * HID;             // NPAD*128 bf16 (lin conv1, net t)
    unsigned short* Hb1 = Lb2 + (size_t)N_PAD * HID;             // NPAD*128 bf16 (h, net s)
    unsigned short* Hb2 = Hb1 + (size_t)N_PAD * HID;             // NPAD*128 bf16 (h, net t)
    // aliases (lifetime-disjoint):
    //   conv3 lin overlays conv1 lin; z overlays h
    //   binned edge records overlay Hb (dead before gather_relu writes Hb)
    unsigned short* L2b1 = Lb1;                                  // NPAD*64 bf16 (lin conv3, s)
    unsigned short* L2b2 = Lb2;
    unsigned short* Zb1  = Hb1;                                  // NPAD*64 bf16 (z copy, s)
    unsigned short* Zb2  = Hb2;
    uint2* binned       = (uint2*)Hb1;                           // NBUCK*BCAP*8B = 9.6 MB
    unsigned short* Wp1 = Hb2 + (size_t)N_PAD * HID;             // 128*128 bf16
    unsigned short* Wp2 = Wp1 + 128 * HID;                       // 128*128 bf16
    unsigned short* W3p = Wp2 + 128 * HID;                       // 128*64 bf16
    float* dis          = (float*)(W3p + 128 * OUT_D);           // 2N f
    uint4* node_info    = (uint4*)(dis + TOTN);                  // 2N uint4 (16B aligned: offset from ws base is even*4B.. ensured below)
    int*   ebuf         = (int*)(node_info + TOTN);              // NBUCK*BCAP_PAD + slack
    int*   tail         = ebuf + NBUCK * BCAP_PAD + 8;           // NBUCK i

    float* out = (float*)d_out;
    float* out_zs = out;                                 // N*64
    float* out_zt = out + (size_t)N_NODES * OUT_D;       // N*64
    float* out_ps = out + 2 * (size_t)N_NODES * OUT_D;   // E
    float* out_pt = out_ps + N_EDGES;                    // E

    // ---- CSR build via bucket binning (fixed-stride buckets; no inter-bucket scan) ----
    hipMemsetAsync(tail, 0, NBUCK * sizeof(int), stream);
    bin_edges<<<BIN_NBLK + PACK_BLK, 256, 0, stream>>>(s_ei, t_ei, tail, binned,
                                                       W1, W2, W3, Wp1, Wp2, W3p);
    build_csr<<<NBUCK, 256, 0, stream>>>(tail, binned, node_info, dis, ebuf);

    // ---- conv1/conv2 lin: fused fp32->bf16 convert + MFMA GEMM, both nets ----
    mfma_gemm_f32<HID><<<dim3(ROW_BLKS, 2), 256, 0, stream>>>(
        xs, xt, Wp1, Wp2, Lb1, Lb2, N_NODES);

    // ---- gather + bias + relu, both nets ----
    gather_relu_128_v3<<<dim3((N_NODES + 15) / 16, 2), 256, 0, stream>>>(
        Lb1, Lb2, node_info, ebuf, dis, b1, b2, Hb1, Hb2, N_NODES);

    // ---- conv3 lin: MFMA GEMM (bf16 in), both nets ----
    mfma_gemm_bf<OUT_D><<<dim3(ROW_BLKS, 2), 256, 0, stream>>>(
        Hb1, Hb2, W3p, L2b1, L2b2, N_NODES);

    // ---- gather -> z (fp32 out) + bf16 copy, both nets ----
    gather_out_64_v3<<<dim3((N_NODES + 31) / 32, 2), 256, 0, stream>>>(
        L2b1, L2b2, node_info, ebuf, dis, b3, out_zs, out_zt, Zb1, Zb2, N_NODES);

    // ---- decoder, both nets ----
    decoder2<<<dim3((int)(((size_t)N_EDGES * 8 + 255) / 256), 2), 256, 0, stream>>>(
        Zb1, Zb2, s_ei, t_ei, out_ps, out_pt);
}